// Round 4
// baseline (376.442 us; speedup 1.0000x reference)
//
#include <hip/hip_runtime.h>
#include <hip/hip_bf16.h>
#include <string.h>

#define NNODE 50000
#define NEDGE 1600000
#define INF   256
#define NH    4
#define EF    64
#define NET   5

#define NBUCK 782     // bucket = hi>>6 (64 nodes each); 50000/64 -> 0..781
#define BCAP  2560    // per-bucket capacity; mean 2048, sd ~45 -> 11 sigma
#define EPB   2048    // edges per partition block
#define PBLK  782     // partition blocks (782*2048 >= E)
#define BKS   784     // padded bucket-row stride
#define RDB   1563    // rowdot blocks per side, 32 rows each (1563*32 >= 50000)

typedef unsigned short u16t;
typedef __attribute__((ext_vector_type(8))) short short8;
typedef __attribute__((ext_vector_type(4))) float f32x4;

__device__ __forceinline__ float b2f(u16t u) {
    union { unsigned int i; float f; } v; v.i = ((unsigned int)u) << 16; return v.f;
}
__device__ __forceinline__ u16t f2b(float f) {
    __hip_bfloat16 h = __float2bfloat16(f);
    u16t u; memcpy(&u, &h, 2); return u;
}

// ---------------------------------------------------------------------------
__global__ void k_detect(const int* __restrict__ el, const int* __restrict__ ety,
                         int* __restrict__ flag) {
    int tid = threadIdx.x;
    int w = tid >> 6, lane = tid & 63;
    const int* p = (w == 0) ? el : ety;
    int x = p[2 * lane + 1];
    unsigned long long b = __ballot(x != 0);
    if (lane == 0) flag[w] = (b == 0ULL) ? 1 : 0;
}

// ---------------------------------------------------------------------------
__global__ void k_prep(const float* __restrict__ W, const float* __restrict__ We,
                       const float* __restrict__ emb, const float* __restrict__ al,
                       const float* __restrict__ ar, const float* __restrict__ ae,
                       float* __restrict__ wl, float* __restrict__ wr,
                       float* __restrict__ he) {
    __shared__ float wes[EF * NH];
    int tid = threadIdx.x;
    {
        int k = tid;
        for (int h = 0; h < NH; h++) {
            float accl = 0.f, accr = 0.f;
            for (int d = 0; d < 32; d++) {
                float w = W[k * 128 + h * 32 + d];
                accl += w * al[h * 32 + d];
                accr += w * ar[h * 32 + d];
            }
            wl[k * NH + h] = accl;
            wr[k * NH + h] = accr;
        }
    }
    if (tid < EF) {
        int k = tid;
        for (int h = 0; h < NH; h++) {
            float s = 0.f;
            for (int d = 0; d < EF; d++)
                s += We[k * (NH * EF) + h * EF + d] * ae[h * EF + d];
            wes[k * NH + h] = s;
        }
    }
    __syncthreads();
    if (tid < NET * NH) {
        int t = tid / NH, h = tid % NH;
        float s = 0.f;
        for (int k = 0; k < EF; k++)
            s += emb[t * EF + k] * wes[k * NH + h];
        he[tid] = s;
    }
}

// ---------------------------------------------------------------------------
__global__ void k_prepw(const float* __restrict__ W, u16t* __restrict__ Wfrag) {
    int idx = blockIdx.x * 256 + threadIdx.x;  // 0..32767
    int j    = idx & 7;
    int lane = (idx >> 3) & 63;
    int ks   = (idx >> 9) & 7;
    int tile = idx >> 12;
    int n = tile * 16 + (lane & 15);
    int k = ks * 32 + (lane >> 4) * 8 + j;
    Wfrag[idx] = f2b(W[k * 128 + n]);
}

// ---------------------------------------------------------------------------
// k_fuseA: [0,PBLK) bucket-partition of edges, DETERMINISTIC (zero global
// atomics): block b stages its bucket-sorted records to bucketbuf[b*EPB ...]
// (coalesced) and writes per-(block,bucket) counts/offsets hist2d/loff2d.
// [PBLK, PBLK+RDB) rowdot(head->hl); [PBLK+RDB, PBLK+2*RDB) rowdot(tail->hr).
// Record = ti | (hi&63)<<16 | ty<<22 ; bucket = hi>>6.
// ---------------------------------------------------------------------------
__global__ void k_fuseA(const float* __restrict__ head, const float* __restrict__ tail,
                        const float* __restrict__ wl, const float* __restrict__ wr,
                        const int* __restrict__ el, const int* __restrict__ ety,
                        const int* __restrict__ flag,
                        int* __restrict__ hist2d, int* __restrict__ loff2d,
                        unsigned int* __restrict__ bucketbuf,
                        float* __restrict__ hl, float* __restrict__ hr) {
    __shared__ unsigned int srec[EPB];
    __shared__ int hist[BKS];
    __shared__ int loff[BKS];
    __shared__ int psum[256];
    int b = blockIdx.x;
    int tid = threadIdx.x;
    if (b < PBLK) {
        int base = b * EPB;
        int wf = flag[0], wt = flag[1];
        for (int i = tid; i < BKS; i += 256) hist[i] = 0;
        __syncthreads();
        unsigned int rec[8];
        unsigned int br[8];
#pragma unroll
        for (int i = 0; i < 8; i++) {
            int e = base + i * 256 + tid;
            br[i] = 0xffffffffu;
            rec[i] = 0;
            if (e < NEDGE) {
                int hi = wf ? el[2 * (long long)e]           : el[e];
                int ti = wf ? el[2 * ((long long)NEDGE + e)] : el[NEDGE + e];
                int ty = wt ? ety[2 * (long long)e]          : ety[e];
                int bk = hi >> 6;
                int r = atomicAdd(&hist[bk], 1);
                rec[i] = (unsigned)ti | ((unsigned)(hi & 63) << 16) | ((unsigned)ty << 22);
                br[i]  = (unsigned)bk | ((unsigned)r << 16);
            }
        }
        __syncthreads();
        int s4[4]; int tsum = 0;
        if (tid < 196) {
#pragma unroll
            for (int j = 0; j < 4; j++) { s4[j] = hist[4 * tid + j]; tsum += s4[j]; }
        }
        psum[tid] = (tid < 196) ? tsum : 0;
        __syncthreads();
        for (int off = 1; off < 256; off <<= 1) {
            int v = (tid >= off) ? psum[tid - off] : 0;
            __syncthreads();
            psum[tid] += v;
            __syncthreads();
        }
        if (tid < 196) {
            int run = tid ? psum[tid - 1] : 0;
#pragma unroll
            for (int j = 0; j < 4; j++) {
                int bk = 4 * tid + j;
                loff[bk] = run;
                hist2d[b * BKS + bk] = s4[j];
                loff2d[b * BKS + bk] = run;
                run += s4[j];
            }
        }
        __syncthreads();
#pragma unroll
        for (int i = 0; i < 8; i++) {
            if (br[i] != 0xffffffffu) {
                int bk = br[i] & 0xffff;
                int r  = br[i] >> 16;
                srec[loff[bk] + r] = rec[i];
            }
        }
        __syncthreads();
        int tot = psum[255];
        for (int i = tid; i < tot; i += 256)
            bucketbuf[(size_t)b * EPB + i] = srec[i];
    } else {
        int bb = b - PBLK;
        int ishead = (bb < RDB);
        const float* X  = ishead ? head : tail;
        const float* wv = ishead ? wl : wr;
        float* o        = ishead ? hl : hr;
        int rowbase = (ishead ? bb : bb - RDB) * 32;
        int wave = tid >> 6;
        int g = (tid >> 4) & 3;
        int l = tid & 15;
        const float4* wv4 = (const float4*)wv;
        float4 acc[2];
#pragma unroll
        for (int rr = 0; rr < 2; rr++) {
            acc[rr].x = 0.f; acc[rr].y = 0.f; acc[rr].z = 0.f; acc[rr].w = 0.f;
            int row = rowbase + rr * 16 + wave * 4 + g;
            if (row < NNODE) {
                const float* xp = X + (size_t)row * INF + l * 4;
#pragma unroll
                for (int c = 0; c < 4; c++) {
                    float4 xv = *(const float4*)(xp + c * 64);
                    float xs[4] = {xv.x, xv.y, xv.z, xv.w};
#pragma unroll
                    for (int j = 0; j < 4; j++) {
                        float4 wvv = wv4[c * 64 + l * 4 + j];
                        acc[rr].x += xs[j] * wvv.x;
                        acc[rr].y += xs[j] * wvv.y;
                        acc[rr].z += xs[j] * wvv.z;
                        acc[rr].w += xs[j] * wvv.w;
                    }
                }
            }
        }
#pragma unroll
        for (int rr = 0; rr < 2; rr++) {
            // masks 8/4/2/1 never cross the 16-lane group boundary
#pragma unroll
            for (int off = 8; off > 0; off >>= 1) {
                acc[rr].x += __shfl_xor(acc[rr].x, off);
                acc[rr].y += __shfl_xor(acc[rr].y, off);
                acc[rr].z += __shfl_xor(acc[rr].z, off);
                acc[rr].w += __shfl_xor(acc[rr].w, off);
            }
            int row = rowbase + rr * 16 + wave * 4 + g;
            if (l == 0 && row < NNODE) ((float4*)o)[row] = acc[rr];
        }
    }
}

// ---------------------------------------------------------------------------
// k_bsum: cursor[bk] = sum_b hist2d[b][bk]  (replaces global atomics)
// ---------------------------------------------------------------------------
__global__ void k_bsum(const int* __restrict__ hist2d, int* __restrict__ cursor) {
    __shared__ int red[256];
    int bk = blockIdx.x;          // 0..NBUCK-1
    int tid = threadIdx.x;
    int s = 0;
    for (int sb = tid; sb < PBLK; sb += 256) s += hist2d[sb * BKS + bk];
    red[tid] = s;
    __syncthreads();
    for (int off = 128; off > 0; off >>= 1) {
        if (tid < off) red[tid] += red[tid + off];
        __syncthreads();
    }
    if (tid == 0) cursor[bk] = red[0];
}

// ---------------------------------------------------------------------------
__global__ void k_bscan(const int* __restrict__ cursor, int* __restrict__ bstart,
                        int* __restrict__ row_start) {
    __shared__ int psum[256];
    int tid = threadIdx.x;
    int s4[4]; int tsum = 0;
    if (tid < 196) {
#pragma unroll
        for (int j = 0; j < 4; j++) {
            int bk = 4 * tid + j;
            s4[j] = (bk < NBUCK) ? cursor[bk] : 0;
            tsum += s4[j];
        }
    }
    psum[tid] = (tid < 196) ? tsum : 0;
    __syncthreads();
    for (int off = 1; off < 256; off <<= 1) {
        int v = (tid >= off) ? psum[tid - off] : 0;
        __syncthreads();
        psum[tid] += v;
        __syncthreads();
    }
    if (tid < 196) {
        int run = tid ? psum[tid - 1] : 0;
#pragma unroll
        for (int j = 0; j < 4; j++) {
            int bk = 4 * tid + j;
            if (bk < NBUCK) bstart[bk] = run;
            run += s4[j];
        }
    }
    if (tid == 255) {
        bstart[NBUCK] = psum[255];
        row_start[NNODE] = psum[255];
    }
}

// ---------------------------------------------------------------------------
// k_fuseB: [0,3125) MFMA gemm; [3125,3907) per-bucket gather (from block
// slices via hist2d/loff2d) + LDS counting-sort -> cpack runs + row_start.
// ---------------------------------------------------------------------------
__global__ void k_fuseB(const float* __restrict__ X, const u16t* __restrict__ Wfrag,
                        u16t* __restrict__ H, const unsigned int* __restrict__ bucketbuf,
                        const int* __restrict__ hist2d, const int* __restrict__ loff2d,
                        const int* __restrict__ bstart,
                        unsigned int* __restrict__ cpack, int* __restrict__ row_start) {
    __shared__ __attribute__((aligned(16))) u16t alds[16 * 264];
    __shared__ unsigned int lrec[BCAP];
    __shared__ unsigned int lord[BCAP];
    __shared__ int psum[256];
    __shared__ int cnt[64];
    __shared__ int sc[64];
    int b = blockIdx.x;
    int tid = threadIdx.x;
    if (b < 3125) {
        int rowbase = b * 16;
        for (int i = tid; i < 1024; i += 256) {
            int row = i >> 6;
            int kc = (i & 63) * 4;
            float4 v = *(const float4*)(X + (size_t)(rowbase + row) * INF + kc);
            u16t* d = alds + row * 264 + kc;
            d[0] = f2b(v.x); d[1] = f2b(v.y); d[2] = f2b(v.z); d[3] = f2b(v.w);
        }
        __syncthreads();
        int wave = tid >> 6, lane = tid & 63;
        int m = lane & 15, quad = lane >> 4;
        int t0 = wave * 2, t1 = t0 + 1;
        f32x4 acc0 = {0.f, 0.f, 0.f, 0.f};
        f32x4 acc1 = {0.f, 0.f, 0.f, 0.f};
#pragma unroll
        for (int ks = 0; ks < 8; ks++) {
            short8 a  = *(const short8*)(alds + m * 264 + ks * 32 + quad * 8);
            short8 b0 = *(const short8*)(Wfrag + (((t0 * 8 + ks) * 64 + lane) << 3));
            short8 b1 = *(const short8*)(Wfrag + (((t1 * 8 + ks) * 64 + lane) << 3));
            acc0 = __builtin_amdgcn_mfma_f32_16x16x32_bf16(a, b0, acc0, 0, 0, 0);
            acc1 = __builtin_amdgcn_mfma_f32_16x16x32_bf16(a, b1, acc1, 0, 0, 0);
        }
        u16t* Hp = H + (size_t)rowbase * 128;
#pragma unroll
        for (int r = 0; r < 4; r++) {
            int row = quad * 4 + r;
            Hp[(size_t)row * 128 + t0 * 16 + m] = f2b(acc0[r]);
            Hp[(size_t)row * 128 + t1 * 16 + m] = f2b(acc1[r]);
        }
    } else {
        int q = b - 3125;                 // bucket 0..781
        int bs = bstart[q];
        // gather this bucket's runs from the 782 block slices
        int c4[4], o4[4]; int tsum = 0;
        if (tid < 196) {
#pragma unroll
            for (int j = 0; j < 4; j++) {
                int sb = 4 * tid + j;
                c4[j] = 0; o4[j] = 0;
                if (sb < PBLK) {
                    c4[j] = hist2d[sb * BKS + q];
                    o4[j] = loff2d[sb * BKS + q];
                }
                tsum += c4[j];
            }
        }
        psum[tid] = (tid < 196) ? tsum : 0;
        __syncthreads();
        for (int off = 1; off < 256; off <<= 1) {
            int v = (tid >= off) ? psum[tid - off] : 0;
            __syncthreads();
            psum[tid] += v;
            __syncthreads();
        }
        if (tid < 196) {
            int run = tid ? psum[tid - 1] : 0;
#pragma unroll
            for (int j = 0; j < 4; j++) {
                int sb = 4 * tid + j;
                for (int k = 0; k < c4[j]; k++) {
                    int d = run + k;
                    if (d < BCAP)
                        lrec[d] = bucketbuf[(size_t)sb * EPB + o4[j] + k];
                }
                run += c4[j];
            }
        }
        if (tid < 64) cnt[tid] = 0;
        __syncthreads();
        int nrec = psum[255];
        if (nrec > BCAP) nrec = BCAP;
        unsigned int myr[10];
        int k2 = 0;
        for (int i = tid; i < nrec; i += 256) {
            int n = (lrec[i] >> 16) & 63;
            myr[k2++] = atomicAdd(&cnt[n], 1);
        }
        __syncthreads();
        if (tid < 64) sc[tid] = cnt[tid];
        __syncthreads();
        for (int off = 1; off < 64; off <<= 1) {
            int v = (tid >= off && tid < 64) ? sc[tid - off] : 0;
            __syncthreads();
            if (tid < 64) sc[tid] += v;
            __syncthreads();
        }
        k2 = 0;
        for (int i = tid; i < nrec; i += 256) {
            unsigned int rc = lrec[i];
            int n  = (rc >> 16) & 63;
            int ti = rc & 0xffff;
            int ty = rc >> 22;
            int pos = (sc[n] - cnt[n]) + (int)myr[k2++];
            lord[pos] = ((unsigned)ty << 16) | (unsigned)ti;
        }
        __syncthreads();
        for (int i = tid; i < nrec; i += 256)
            cpack[bs + i] = lord[i];
        if (tid < 64) {
            int node = q * 64 + tid;
            if (node < NNODE) row_start[node] = bs + (sc[tid] - cnt[tid]);
        }
    }
}

// ---------------------------------------------------------------------------
// k_agg: one wave per node. Two-phase per 16-edge chunk:
//  phase1: lane h*16+i computes exp for (edge i, head h) exactly once ->
//          LDS + per-lane denom partial;
//  phase2: ti broadcast via readlane (SGPR base addressing), e broadcast via
//          LDS read with immediate offset; 2 converts + 2 FMAs per edge.
// Wave-private LDS; no __syncthreads needed (per-wave in-order LDS).
// ---------------------------------------------------------------------------
__global__ void k_agg(const int* __restrict__ rs, const unsigned int* __restrict__ cpack,
                      const float* __restrict__ hl, const float* __restrict__ hr,
                      const float* __restrict__ heg, const u16t* __restrict__ ht,
                      float* __restrict__ den, float2* __restrict__ out) {
    __shared__ float hes[NET * NH];
    __shared__ float lds_e[4][64];
    int tid = threadIdx.x;
    if (tid < NET * NH) hes[tid] = heg[tid];
    __syncthreads();
    int wave = tid >> 6, lane = tid & 63;
    int node = blockIdx.x * 4 + wave;
    int start = rs[node], end = rs[node + 1];
    int h = lane >> 4;
    int i16 = lane & 15;
    float hlv = hl[node * 4 + h];
    float a0 = 0.f, a1 = 0.f, spart = 0.f;
    const u16t* htl = ht + (lane << 1);
    for (int base = start; base < end; base += 16) {
        int rem = end - base;
        if (rem > 16) rem = 16;
        // ---- phase 1: one exp per (edge, head), no redundancy ----
        int jj = base + (i16 < rem ? i16 : 0);
        unsigned c = cpack[jj];
        int ti = c & 0xffff;
        int ty = c >> 16;
        float att = hlv + hr[ti * 4 + h] + hes[ty * 4 + h];
        att = att > 0.f ? att : 0.2f * att;
        float e = (i16 < rem) ? __expf(att) : 0.f;
        spart += e;
        lds_e[wave][lane] = e;
        __builtin_amdgcn_wave_barrier();
        // ---- phase 2: accumulate; ti via readlane (scalar), e via LDS bcast
        const float* ebase = &lds_e[wave][lane & 48];
#pragma unroll
        for (int i = 0; i < 16; i++) {
            if (i >= rem) break;
            int tis = __builtin_amdgcn_readlane(ti, i);      // uniform -> SGPR
            unsigned hv = *(const unsigned*)(htl + ((size_t)(unsigned)tis << 7));
            float ee = ebase[i];
            union { unsigned u; float f; } lo, hi;
            lo.u = hv << 16;
            hi.u = hv & 0xffff0000u;
            a0 += ee * lo.f;
            a1 += ee * hi.f;
        }
        __builtin_amdgcn_wave_barrier();
    }
    // denom: reduce spart across the 16-lane head group
    float s = spart;
#pragma unroll
    for (int off = 8; off > 0; off >>= 1) s += __shfl_xor(s, off);
    if ((lane & 15) == 0) den[node * 4 + h] = s;
    float o0 = 0.f, o1 = 0.f;
    if (s > 0.f) { o0 = a0 / s; o1 = a1 / s; }
    o0 = o0 > 0.f ? o0 : expm1f(o0);
    o1 = o1 > 0.f ? o1 : expm1f(o1);
    float2 ov = {o0, o1};
    out[(size_t)node * 64 + lane] = ov;
}

// ---------------------------------------------------------------------------
__global__ void k_alpha(const int* __restrict__ el, const int* __restrict__ ety,
                        const int* __restrict__ flag,
                        const float* __restrict__ hl, const float* __restrict__ hr,
                        const float* __restrict__ heg, const float* __restrict__ den,
                        float* __restrict__ alpha) {
    __shared__ float hes[NET * NH];
    int tid = threadIdx.x;
    if (tid < NET * NH) hes[tid] = heg[tid];
    __syncthreads();
    int wf = flag[0], wt = flag[1];
    int e = blockIdx.x * 256 + tid;
    int hi = wf ? el[2 * (long long)e]           : el[e];
    int ti = wf ? el[2 * ((long long)NEDGE + e)] : el[NEDGE + e];
    int ty = wt ? ety[2 * (long long)e]          : ety[e];
    float4 l = ((const float4*)hl)[hi];
    float4 r = ((const float4*)hr)[ti];
    float4 d = ((const float4*)den)[hi];
    float v0 = l.x + r.x + hes[ty * 4 + 0];
    float v1 = l.y + r.y + hes[ty * 4 + 1];
    float v2 = l.z + r.z + hes[ty * 4 + 2];
    float v3 = l.w + r.w + hes[ty * 4 + 3];
    v0 = v0 > 0.f ? v0 : 0.2f * v0;
    v1 = v1 > 0.f ? v1 : 0.2f * v1;
    v2 = v2 > 0.f ? v2 : 0.2f * v2;
    v3 = v3 > 0.f ? v3 : 0.2f * v3;
    float4 o;
    o.x = d.x > 0.f ? __expf(v0) / d.x : 0.f;
    o.y = d.y > 0.f ? __expf(v1) / d.y : 0.f;
    o.z = d.z > 0.f ? __expf(v2) / d.z : 0.f;
    o.w = d.w > 0.f ? __expf(v3) / d.w : 0.f;
    ((float4*)alpha)[e] = o;
}

// ---------------------------------------------------------------------------
extern "C" void kernel_launch(void* const* d_in, const int* in_sizes, int n_in,
                              void* d_out, int out_size, void* d_ws, size_t ws_size,
                              hipStream_t stream) {
    const float* head = (const float*)d_in[0];
    const float* tail = (const float*)d_in[1];
    const float* W    = (const float*)d_in[2];
    const float* We   = (const float*)d_in[3];
    const float* emb  = (const float*)d_in[4];
    const float* al   = (const float*)d_in[5];
    const float* ar   = (const float*)d_in[6];
    const float* ae   = (const float*)d_in[7];
    const int*   el   = (const int*)d_in[8];
    const int*   ety  = (const int*)d_in[9];

    float* ws = (float*)d_ws;
    // ws layout (f32-slot offsets), ~2.7 MiB total
    float* hl       = ws;                       // 200,000
    float* hr       = ws + 200000;              // 200,000
    float* wl       = ws + 400000;              // 1,024
    float* wr       = ws + 401024;              // 1,024
    float* heg      = ws + 402048;              // 32
    int*   flag     = (int*)(ws + 402080);      // 16
    int*   bstart   = (int*)(ws + 402096);      // 784
    int*   cursor   = (int*)(ws + 402880);      // 784
    float* den      = ws + 403664;              // 200,000
    int*   row_start= (int*)(ws + 603664);      // 50,001 (+3 pad)
    u16t*  Wfrag    = (u16t*)(ws + 653668);     // 32,768 bf16 (16,384 f32)

    // d_out: f32 out [50000,128] then f32 alpha [E,4]
    float* outp   = (float*)d_out;              // 6,400,000 f32
    float* alphap = (float*)d_out + 6400000;    // 6,400,000 f32
    // scratch in alpha region until k_alpha overwrites: htail + cpack
    u16t*         htail = (u16t*)alphap;                       // 6.4M bf16
    unsigned int* cpack = (unsigned int*)(alphap + 3200000);   // 1.6M u32
    // scratch in out region (consumed by k_fuseB before k_agg writes out):
    // bucketbuf (block slices) + hist2d + loff2d
    unsigned int* bucketbuf = (unsigned int*)outp;             // 782*2048 u32 = 6.4 MB
    int* hist2d = (int*)outp + 1601536;                        // 782*784 ints
    int* loff2d = hist2d + 613088;                             // 782*784 ints

    k_detect<<<1, 128, 0, stream>>>(el, ety, flag);
    k_prep<<<1, 256, 0, stream>>>(W, We, emb, al, ar, ae, wl, wr, heg);
    k_prepw<<<128, 256, 0, stream>>>(W, Wfrag);
    k_fuseA<<<PBLK + 2 * RDB, 256, 0, stream>>>(head, tail, wl, wr, el, ety, flag,
                                                hist2d, loff2d, bucketbuf, hl, hr);
    k_bsum<<<NBUCK, 256, 0, stream>>>(hist2d, cursor);
    k_bscan<<<1, 256, 0, stream>>>(cursor, bstart, row_start);
    k_fuseB<<<3125 + NBUCK, 256, 0, stream>>>(tail, Wfrag, htail, bucketbuf,
                                              hist2d, loff2d, bstart, cpack, row_start);
    k_agg<<<NNODE / 4, 256, 0, stream>>>(row_start, cpack, hl, hr, heg, htail,
                                         den, (float2*)outp);
    k_alpha<<<NEDGE / 256, 256, 0, stream>>>(el, ety, flag, hl, hr, heg, den, alphap);
}

// Round 5
// 338.356 us; speedup vs baseline: 1.1126x; 1.1126x over previous
//
#include <hip/hip_runtime.h>
#include <hip/hip_bf16.h>
#include <string.h>

#define NNODE 50000
#define NEDGE 1600000
#define INF   256
#define NH    4
#define EF    64
#define NET   5

#define NBUCK 782     // bucket = hi>>6 (64 nodes each); 50000/64 -> 0..781
#define BCAP  2560    // per-bucket capacity; mean 2048, sd ~45 -> 11 sigma
#define EPB   2048    // edges per partition block
#define PBLK  782     // partition blocks (782*2048 >= E)
#define BKS   784     // padded bucket-row stride
#define RDB   1563    // rowdot blocks per side, 32 rows each (1563*32 >= 50000)

typedef unsigned short u16t;
typedef __attribute__((ext_vector_type(8))) short short8;
typedef __attribute__((ext_vector_type(4))) float f32x4;

__device__ __forceinline__ float b2f(u16t u) {
    union { unsigned int i; float f; } v; v.i = ((unsigned int)u) << 16; return v.f;
}
__device__ __forceinline__ u16t f2b(float f) {
    __hip_bfloat16 h = __float2bfloat16(f);
    u16t u; memcpy(&u, &h, 2); return u;
}

// ---------------------------------------------------------------------------
__global__ void k_detect(const int* __restrict__ el, const int* __restrict__ ety,
                         int* __restrict__ flag) {
    int tid = threadIdx.x;
    int w = tid >> 6, lane = tid & 63;
    const int* p = (w == 0) ? el : ety;
    int x = p[2 * lane + 1];
    unsigned long long b = __ballot(x != 0);
    if (lane == 0) flag[w] = (b == 0ULL) ? 1 : 0;
}

// ---------------------------------------------------------------------------
__global__ void k_prep(const float* __restrict__ W, const float* __restrict__ We,
                       const float* __restrict__ emb, const float* __restrict__ al,
                       const float* __restrict__ ar, const float* __restrict__ ae,
                       float* __restrict__ wl, float* __restrict__ wr,
                       float* __restrict__ he) {
    __shared__ float wes[EF * NH];
    int tid = threadIdx.x;
    {
        int k = tid;
        for (int h = 0; h < NH; h++) {
            float accl = 0.f, accr = 0.f;
            for (int d = 0; d < 32; d++) {
                float w = W[k * 128 + h * 32 + d];
                accl += w * al[h * 32 + d];
                accr += w * ar[h * 32 + d];
            }
            wl[k * NH + h] = accl;
            wr[k * NH + h] = accr;
        }
    }
    if (tid < EF) {
        int k = tid;
        for (int h = 0; h < NH; h++) {
            float s = 0.f;
            for (int d = 0; d < EF; d++)
                s += We[k * (NH * EF) + h * EF + d] * ae[h * EF + d];
            wes[k * NH + h] = s;
        }
    }
    __syncthreads();
    if (tid < NET * NH) {
        int t = tid / NH, h = tid % NH;
        float s = 0.f;
        for (int k = 0; k < EF; k++)
            s += emb[t * EF + k] * wes[k * NH + h];
        he[tid] = s;
    }
}

// ---------------------------------------------------------------------------
__global__ void k_prepw(const float* __restrict__ W, u16t* __restrict__ Wfrag) {
    int idx = blockIdx.x * 256 + threadIdx.x;  // 0..32767
    int j    = idx & 7;
    int lane = (idx >> 3) & 63;
    int ks   = (idx >> 9) & 7;
    int tile = idx >> 12;
    int n = tile * 16 + (lane & 15);
    int k = ks * 32 + (lane >> 4) * 8 + j;
    Wfrag[idx] = f2b(W[k * 128 + n]);
}

// ---------------------------------------------------------------------------
// k_fuseA: [0,PBLK) bucket-partition of edges, DETERMINISTIC (zero global
// atomics): block b stages its bucket-sorted records to bucketbuf[b*EPB ...]
// (coalesced) and writes per-(block,bucket) counts/offsets hist2d/loff2d.
// [PBLK, PBLK+RDB) rowdot(head->hl); [PBLK+RDB, PBLK+2*RDB) rowdot(tail->hr).
// Record = ti | (hi&63)<<16 | ty<<22 ; bucket = hi>>6.
// ---------------------------------------------------------------------------
__global__ void k_fuseA(const float* __restrict__ head, const float* __restrict__ tail,
                        const float* __restrict__ wl, const float* __restrict__ wr,
                        const int* __restrict__ el, const int* __restrict__ ety,
                        const int* __restrict__ flag,
                        int* __restrict__ hist2d, int* __restrict__ loff2d,
                        unsigned int* __restrict__ bucketbuf,
                        float* __restrict__ hl, float* __restrict__ hr) {
    __shared__ unsigned int srec[EPB];
    __shared__ int hist[BKS];
    __shared__ int loff[BKS];
    __shared__ int psum[256];
    int b = blockIdx.x;
    int tid = threadIdx.x;
    if (b < PBLK) {
        int base = b * EPB;
        int wf = flag[0], wt = flag[1];
        for (int i = tid; i < BKS; i += 256) hist[i] = 0;
        __syncthreads();
        unsigned int rec[8];
        unsigned int br[8];
#pragma unroll
        for (int i = 0; i < 8; i++) {
            int e = base + i * 256 + tid;
            br[i] = 0xffffffffu;
            rec[i] = 0;
            if (e < NEDGE) {
                int hi = wf ? el[2 * (long long)e]           : el[e];
                int ti = wf ? el[2 * ((long long)NEDGE + e)] : el[NEDGE + e];
                int ty = wt ? ety[2 * (long long)e]          : ety[e];
                int bk = hi >> 6;
                int r = atomicAdd(&hist[bk], 1);
                rec[i] = (unsigned)ti | ((unsigned)(hi & 63) << 16) | ((unsigned)ty << 22);
                br[i]  = (unsigned)bk | ((unsigned)r << 16);
            }
        }
        __syncthreads();
        int s4[4]; int tsum = 0;
        if (tid < 196) {
#pragma unroll
            for (int j = 0; j < 4; j++) { s4[j] = hist[4 * tid + j]; tsum += s4[j]; }
        }
        psum[tid] = (tid < 196) ? tsum : 0;
        __syncthreads();
        for (int off = 1; off < 256; off <<= 1) {
            int v = (tid >= off) ? psum[tid - off] : 0;
            __syncthreads();
            psum[tid] += v;
            __syncthreads();
        }
        if (tid < 196) {
            int run = tid ? psum[tid - 1] : 0;
#pragma unroll
            for (int j = 0; j < 4; j++) {
                int bk = 4 * tid + j;
                loff[bk] = run;
                hist2d[b * BKS + bk] = s4[j];
                loff2d[b * BKS + bk] = run;
                run += s4[j];
            }
        }
        __syncthreads();
#pragma unroll
        for (int i = 0; i < 8; i++) {
            if (br[i] != 0xffffffffu) {
                int bk = br[i] & 0xffff;
                int r  = br[i] >> 16;
                srec[loff[bk] + r] = rec[i];
            }
        }
        __syncthreads();
        int tot = psum[255];
        for (int i = tid; i < tot; i += 256)
            bucketbuf[(size_t)b * EPB + i] = srec[i];
    } else {
        int bb = b - PBLK;
        int ishead = (bb < RDB);
        const float* X  = ishead ? head : tail;
        const float* wv = ishead ? wl : wr;
        float* o        = ishead ? hl : hr;
        int rowbase = (ishead ? bb : bb - RDB) * 32;
        int wave = tid >> 6;
        int g = (tid >> 4) & 3;
        int l = tid & 15;
        const float4* wv4 = (const float4*)wv;
        float4 acc[2];
#pragma unroll
        for (int rr = 0; rr < 2; rr++) {
            acc[rr].x = 0.f; acc[rr].y = 0.f; acc[rr].z = 0.f; acc[rr].w = 0.f;
            int row = rowbase + rr * 16 + wave * 4 + g;
            if (row < NNODE) {
                const float* xp = X + (size_t)row * INF + l * 4;
#pragma unroll
                for (int c = 0; c < 4; c++) {
                    float4 xv = *(const float4*)(xp + c * 64);
                    float xs[4] = {xv.x, xv.y, xv.z, xv.w};
#pragma unroll
                    for (int j = 0; j < 4; j++) {
                        float4 wvv = wv4[c * 64 + l * 4 + j];
                        acc[rr].x += xs[j] * wvv.x;
                        acc[rr].y += xs[j] * wvv.y;
                        acc[rr].z += xs[j] * wvv.z;
                        acc[rr].w += xs[j] * wvv.w;
                    }
                }
            }
        }
#pragma unroll
        for (int rr = 0; rr < 2; rr++) {
            // masks 8/4/2/1 never cross the 16-lane group boundary
#pragma unroll
            for (int off = 8; off > 0; off >>= 1) {
                acc[rr].x += __shfl_xor(acc[rr].x, off);
                acc[rr].y += __shfl_xor(acc[rr].y, off);
                acc[rr].z += __shfl_xor(acc[rr].z, off);
                acc[rr].w += __shfl_xor(acc[rr].w, off);
            }
            int row = rowbase + rr * 16 + wave * 4 + g;
            if (l == 0 && row < NNODE) ((float4*)o)[row] = acc[rr];
        }
    }
}

// ---------------------------------------------------------------------------
// k_bsum: cursor[bk] = sum_b hist2d[b][bk]  (replaces global atomics)
// ---------------------------------------------------------------------------
__global__ void k_bsum(const int* __restrict__ hist2d, int* __restrict__ cursor) {
    __shared__ int red[256];
    int bk = blockIdx.x;          // 0..NBUCK-1
    int tid = threadIdx.x;
    int s = 0;
    for (int sb = tid; sb < PBLK; sb += 256) s += hist2d[sb * BKS + bk];
    red[tid] = s;
    __syncthreads();
    for (int off = 128; off > 0; off >>= 1) {
        if (tid < off) red[tid] += red[tid + off];
        __syncthreads();
    }
    if (tid == 0) cursor[bk] = red[0];
}

// ---------------------------------------------------------------------------
__global__ void k_bscan(const int* __restrict__ cursor, int* __restrict__ bstart,
                        int* __restrict__ row_start) {
    __shared__ int psum[256];
    int tid = threadIdx.x;
    int s4[4]; int tsum = 0;
    if (tid < 196) {
#pragma unroll
        for (int j = 0; j < 4; j++) {
            int bk = 4 * tid + j;
            s4[j] = (bk < NBUCK) ? cursor[bk] : 0;
            tsum += s4[j];
        }
    }
    psum[tid] = (tid < 196) ? tsum : 0;
    __syncthreads();
    for (int off = 1; off < 256; off <<= 1) {
        int v = (tid >= off) ? psum[tid - off] : 0;
        __syncthreads();
        psum[tid] += v;
        __syncthreads();
    }
    if (tid < 196) {
        int run = tid ? psum[tid - 1] : 0;
#pragma unroll
        for (int j = 0; j < 4; j++) {
            int bk = 4 * tid + j;
            if (bk < NBUCK) bstart[bk] = run;
            run += s4[j];
        }
    }
    if (tid == 255) {
        bstart[NBUCK] = psum[255];
        row_start[NNODE] = psum[255];
    }
}

// ---------------------------------------------------------------------------
// k_fuseB: [0,3125) MFMA gemm; [3125,3907) per-bucket gather (from block
// slices via hist2d/loff2d) + LDS counting-sort -> cpack runs + row_start.
// cpack packing: ty<<18 | ti  (ty pre-shifted so k_agg's hes index is c>>16).
// ---------------------------------------------------------------------------
__global__ void k_fuseB(const float* __restrict__ X, const u16t* __restrict__ Wfrag,
                        u16t* __restrict__ H, const unsigned int* __restrict__ bucketbuf,
                        const int* __restrict__ hist2d, const int* __restrict__ loff2d,
                        const int* __restrict__ bstart,
                        unsigned int* __restrict__ cpack, int* __restrict__ row_start) {
    __shared__ __attribute__((aligned(16))) u16t alds[16 * 264];
    __shared__ unsigned int lrec[BCAP];
    __shared__ unsigned int lord[BCAP];
    __shared__ int psum[256];
    __shared__ int cnt[64];
    __shared__ int sc[64];
    int b = blockIdx.x;
    int tid = threadIdx.x;
    if (b < 3125) {
        int rowbase = b * 16;
        for (int i = tid; i < 1024; i += 256) {
            int row = i >> 6;
            int kc = (i & 63) * 4;
            float4 v = *(const float4*)(X + (size_t)(rowbase + row) * INF + kc);
            u16t* d = alds + row * 264 + kc;
            d[0] = f2b(v.x); d[1] = f2b(v.y); d[2] = f2b(v.z); d[3] = f2b(v.w);
        }
        __syncthreads();
        int wave = tid >> 6, lane = tid & 63;
        int m = lane & 15, quad = lane >> 4;
        int t0 = wave * 2, t1 = t0 + 1;
        f32x4 acc0 = {0.f, 0.f, 0.f, 0.f};
        f32x4 acc1 = {0.f, 0.f, 0.f, 0.f};
#pragma unroll
        for (int ks = 0; ks < 8; ks++) {
            short8 a  = *(const short8*)(alds + m * 264 + ks * 32 + quad * 8);
            short8 b0 = *(const short8*)(Wfrag + (((t0 * 8 + ks) * 64 + lane) << 3));
            short8 b1 = *(const short8*)(Wfrag + (((t1 * 8 + ks) * 64 + lane) << 3));
            acc0 = __builtin_amdgcn_mfma_f32_16x16x32_bf16(a, b0, acc0, 0, 0, 0);
            acc1 = __builtin_amdgcn_mfma_f32_16x16x32_bf16(a, b1, acc1, 0, 0, 0);
        }
        u16t* Hp = H + (size_t)rowbase * 128;
#pragma unroll
        for (int r = 0; r < 4; r++) {
            int row = quad * 4 + r;
            Hp[(size_t)row * 128 + t0 * 16 + m] = f2b(acc0[r]);
            Hp[(size_t)row * 128 + t1 * 16 + m] = f2b(acc1[r]);
        }
    } else {
        int q = b - 3125;                 // bucket 0..781
        int bs = bstart[q];
        // gather this bucket's runs from the 782 block slices
        int c4[4], o4[4]; int tsum = 0;
        if (tid < 196) {
#pragma unroll
            for (int j = 0; j < 4; j++) {
                int sb = 4 * tid + j;
                c4[j] = 0; o4[j] = 0;
                if (sb < PBLK) {
                    c4[j] = hist2d[sb * BKS + q];
                    o4[j] = loff2d[sb * BKS + q];
                }
                tsum += c4[j];
            }
        }
        psum[tid] = (tid < 196) ? tsum : 0;
        __syncthreads();
        for (int off = 1; off < 256; off <<= 1) {
            int v = (tid >= off) ? psum[tid - off] : 0;
            __syncthreads();
            psum[tid] += v;
            __syncthreads();
        }
        if (tid < 196) {
            int run = tid ? psum[tid - 1] : 0;
#pragma unroll
            for (int j = 0; j < 4; j++) {
                int sb = 4 * tid + j;
                for (int k = 0; k < c4[j]; k++) {
                    int d = run + k;
                    if (d < BCAP)
                        lrec[d] = bucketbuf[(size_t)sb * EPB + o4[j] + k];
                }
                run += c4[j];
            }
        }
        if (tid < 64) cnt[tid] = 0;
        __syncthreads();
        int nrec = psum[255];
        if (nrec > BCAP) nrec = BCAP;
        unsigned int myr[10];
        int k2 = 0;
        for (int i = tid; i < nrec; i += 256) {
            int n = (lrec[i] >> 16) & 63;
            myr[k2++] = atomicAdd(&cnt[n], 1);
        }
        __syncthreads();
        if (tid < 64) sc[tid] = cnt[tid];
        __syncthreads();
        for (int off = 1; off < 64; off <<= 1) {
            int v = (tid >= off && tid < 64) ? sc[tid - off] : 0;
            __syncthreads();
            if (tid < 64) sc[tid] += v;
            __syncthreads();
        }
        k2 = 0;
        for (int i = tid; i < nrec; i += 256) {
            unsigned int rc = lrec[i];
            int n  = (rc >> 16) & 63;
            int ti = rc & 0xffff;
            int ty = rc >> 22;
            int pos = (sc[n] - cnt[n]) + (int)myr[k2++];
            lord[pos] = ((unsigned)ty << 18) | (unsigned)ti;
        }
        __syncthreads();
        for (int i = tid; i < nrec; i += 256)
            cpack[bs + i] = lord[i];
        if (tid < 64) {
            int node = q * 64 + tid;
            if (node < NNODE) row_start[node] = bs + (sc[tid] - cnt[tid]);
        }
    }
}

// ---------------------------------------------------------------------------
// k_agg: one wave per node, 16 lanes per head, 4 edges per iteration with
// full ILP (round-3 structure). VALU-slimmed: u32 address arithmetic
// (v_lshl_add + SADDR loads), pre-shifted ty (hes idx = c>>16),
// branchless leaky via fmaxf(x, 0.2x).
// ---------------------------------------------------------------------------
__global__ void k_agg(const int* __restrict__ rs, const unsigned int* __restrict__ cpack,
                      const float* __restrict__ hl, const float* __restrict__ hr,
                      const float* __restrict__ heg, const u16t* __restrict__ ht,
                      float* __restrict__ den, float2* __restrict__ out) {
    __shared__ float hes[NET * NH];
    int tid = threadIdx.x;
    if (tid < NET * NH) hes[tid] = heg[tid];
    __syncthreads();
    int wave = tid >> 6, lane = tid & 63;
    int node = blockIdx.x * 4 + wave;
    int start = rs[node], end = rs[node + 1];
    unsigned h = (unsigned)(lane >> 4);
    unsigned lane2 = (unsigned)(lane << 1);
    float hlv = hl[(unsigned)node * 4u + h];
    const float* hesh = hes + h;           // hes idx = (c>>16) + h, c has ty<<18
    float a0 = 0.f, a1 = 0.f, s = 0.f;
    int j = start;
    for (; j + 4 <= end; j += 4) {
        unsigned c0 = cpack[j], c1 = cpack[j + 1], c2 = cpack[j + 2], c3 = cpack[j + 3];
        unsigned t0 = c0 & 0xffffu, t1 = c1 & 0xffffu;
        unsigned t2 = c2 & 0xffffu, t3 = c3 & 0xffffu;
        float r0 = hr[(t0 << 2) + h], r1 = hr[(t1 << 2) + h];
        float r2 = hr[(t2 << 2) + h], r3 = hr[(t3 << 2) + h];
        unsigned v0 = *(const unsigned*)(ht + ((t0 << 7) + lane2));
        unsigned v1 = *(const unsigned*)(ht + ((t1 << 7) + lane2));
        unsigned v2 = *(const unsigned*)(ht + ((t2 << 7) + lane2));
        unsigned v3 = *(const unsigned*)(ht + ((t3 << 7) + lane2));
        float x0 = hlv + r0 + hesh[c0 >> 16];
        float x1 = hlv + r1 + hesh[c1 >> 16];
        float x2 = hlv + r2 + hesh[c2 >> 16];
        float x3 = hlv + r3 + hesh[c3 >> 16];
        x0 = fmaxf(x0, 0.2f * x0);
        x1 = fmaxf(x1, 0.2f * x1);
        x2 = fmaxf(x2, 0.2f * x2);
        x3 = fmaxf(x3, 0.2f * x3);
        float e0 = __expf(x0), e1 = __expf(x1), e2 = __expf(x2), e3 = __expf(x3);
        union { unsigned u; float f; } w0, w1;
        w0.u = v0 << 16;          w1.u = v0 & 0xffff0000u;
        a0 += e0 * w0.f;          a1 += e0 * w1.f;
        w0.u = v1 << 16;          w1.u = v1 & 0xffff0000u;
        a0 += e1 * w0.f;          a1 += e1 * w1.f;
        w0.u = v2 << 16;          w1.u = v2 & 0xffff0000u;
        a0 += e2 * w0.f;          a1 += e2 * w1.f;
        w0.u = v3 << 16;          w1.u = v3 & 0xffff0000u;
        a0 += e3 * w0.f;          a1 += e3 * w1.f;
        s  += e0 + e1 + e2 + e3;
    }
    for (; j < end; j++) {
        unsigned c = cpack[j];
        unsigned ti = c & 0xffffu;
        float att = hlv + hr[(ti << 2) + h] + hesh[c >> 16];
        att = fmaxf(att, 0.2f * att);
        float exv = __expf(att);
        unsigned hv = *(const unsigned*)(ht + ((ti << 7) + lane2));
        union { unsigned u; float f; } w0, w1;
        w0.u = hv << 16;  w1.u = hv & 0xffff0000u;
        a0 += exv * w0.f;
        a1 += exv * w1.f;
        s  += exv;
    }
    if ((lane & 15) == 0) den[(unsigned)node * 4u + h] = s;
    float o0 = 0.f, o1 = 0.f;
    if (s > 0.f) { o0 = a0 / s; o1 = a1 / s; }
    o0 = o0 > 0.f ? o0 : expm1f(o0);
    o1 = o1 > 0.f ? o1 : expm1f(o1);
    float2 ov = {o0, o1};
    out[(size_t)node * 64 + lane] = ov;
}

// ---------------------------------------------------------------------------
__global__ void k_alpha(const int* __restrict__ el, const int* __restrict__ ety,
                        const int* __restrict__ flag,
                        const float* __restrict__ hl, const float* __restrict__ hr,
                        const float* __restrict__ heg, const float* __restrict__ den,
                        float* __restrict__ alpha) {
    __shared__ float hes[NET * NH];
    int tid = threadIdx.x;
    if (tid < NET * NH) hes[tid] = heg[tid];
    __syncthreads();
    int wf = flag[0], wt = flag[1];
    int e = blockIdx.x * 256 + tid;
    int hi = wf ? el[2 * (long long)e]           : el[e];
    int ti = wf ? el[2 * ((long long)NEDGE + e)] : el[NEDGE + e];
    int ty = wt ? ety[2 * (long long)e]          : ety[e];
    float4 l = ((const float4*)hl)[hi];
    float4 r = ((const float4*)hr)[ti];
    float4 d = ((const float4*)den)[hi];
    float v0 = l.x + r.x + hes[ty * 4 + 0];
    float v1 = l.y + r.y + hes[ty * 4 + 1];
    float v2 = l.z + r.z + hes[ty * 4 + 2];
    float v3 = l.w + r.w + hes[ty * 4 + 3];
    v0 = v0 > 0.f ? v0 : 0.2f * v0;
    v1 = v1 > 0.f ? v1 : 0.2f * v1;
    v2 = v2 > 0.f ? v2 : 0.2f * v2;
    v3 = v3 > 0.f ? v3 : 0.2f * v3;
    float4 o;
    o.x = d.x > 0.f ? __expf(v0) / d.x : 0.f;
    o.y = d.y > 0.f ? __expf(v1) / d.y : 0.f;
    o.z = d.z > 0.f ? __expf(v2) / d.z : 0.f;
    o.w = d.w > 0.f ? __expf(v3) / d.w : 0.f;
    ((float4*)alpha)[e] = o;
}

// ---------------------------------------------------------------------------
extern "C" void kernel_launch(void* const* d_in, const int* in_sizes, int n_in,
                              void* d_out, int out_size, void* d_ws, size_t ws_size,
                              hipStream_t stream) {
    const float* head = (const float*)d_in[0];
    const float* tail = (const float*)d_in[1];
    const float* W    = (const float*)d_in[2];
    const float* We   = (const float*)d_in[3];
    const float* emb  = (const float*)d_in[4];
    const float* al   = (const float*)d_in[5];
    const float* ar   = (const float*)d_in[6];
    const float* ae   = (const float*)d_in[7];
    const int*   el   = (const int*)d_in[8];
    const int*   ety  = (const int*)d_in[9];

    float* ws = (float*)d_ws;
    // ws layout (f32-slot offsets), ~2.7 MiB total
    float* hl       = ws;                       // 200,000
    float* hr       = ws + 200000;              // 200,000
    float* wl       = ws + 400000;              // 1,024
    float* wr       = ws + 401024;              // 1,024
    float* heg      = ws + 402048;              // 32
    int*   flag     = (int*)(ws + 402080);      // 16
    int*   bstart   = (int*)(ws + 402096);      // 784
    int*   cursor   = (int*)(ws + 402880);      // 784
    float* den      = ws + 403664;              // 200,000
    int*   row_start= (int*)(ws + 603664);      // 50,001 (+3 pad)
    u16t*  Wfrag    = (u16t*)(ws + 653668);     // 32,768 bf16 (16,384 f32)

    // d_out: f32 out [50000,128] then f32 alpha [E,4]
    float* outp   = (float*)d_out;              // 6,400,000 f32
    float* alphap = (float*)d_out + 6400000;    // 6,400,000 f32
    // scratch in alpha region until k_alpha overwrites: htail + cpack
    u16t*         htail = (u16t*)alphap;                       // 6.4M bf16
    unsigned int* cpack = (unsigned int*)(alphap + 3200000);   // 1.6M u32
    // scratch in out region (consumed by k_fuseB before k_agg writes out):
    // bucketbuf (block slices) + hist2d + loff2d
    unsigned int* bucketbuf = (unsigned int*)outp;             // 782*2048 u32 = 6.4 MB
    int* hist2d = (int*)outp + 1601536;                        // 782*784 ints
    int* loff2d = hist2d + 613088;                             // 782*784 ints

    k_detect<<<1, 128, 0, stream>>>(el, ety, flag);
    k_prep<<<1, 256, 0, stream>>>(W, We, emb, al, ar, ae, wl, wr, heg);
    k_prepw<<<128, 256, 0, stream>>>(W, Wfrag);
    k_fuseA<<<PBLK + 2 * RDB, 256, 0, stream>>>(head, tail, wl, wr, el, ety, flag,
                                                hist2d, loff2d, bucketbuf, hl, hr);
    k_bsum<<<NBUCK, 256, 0, stream>>>(hist2d, cursor);
    k_bscan<<<1, 256, 0, stream>>>(cursor, bstart, row_start);
    k_fuseB<<<3125 + NBUCK, 256, 0, stream>>>(tail, Wfrag, htail, bucketbuf,
                                              hist2d, loff2d, bstart, cpack, row_start);
    k_agg<<<NNODE / 4, 256, 0, stream>>>(row_start, cpack, hl, hr, heg, htail,
                                         den, (float2*)outp);
    k_alpha<<<NEDGE / 256, 256, 0, stream>>>(el, ety, flag, hl, hr, heg, den, alphap);
}

// Round 6
// 325.967 us; speedup vs baseline: 1.1548x; 1.0380x over previous
//
#include <hip/hip_runtime.h>
#include <hip/hip_bf16.h>
#include <string.h>

#define NNODE 50000
#define NEDGE 1600000
#define INF   256
#define NH    4
#define EF    64
#define NET   5

#define NBUCK 782     // bucket = hi>>6 (64 nodes each); 50000/64 -> 0..781
#define BCAP  2560    // per-bucket capacity; mean 2048, sd ~45 -> 11 sigma
#define EPB   2048    // edges per partition block
#define PBLK  782     // partition blocks (782*2048 >= E)
#define BKS   784     // padded bucket-row stride
#define RDB   1563    // head-rowdot blocks, 32 rows each (1563*32 >= 50000)

typedef unsigned short u16t;
typedef __attribute__((ext_vector_type(8))) short short8;
typedef __attribute__((ext_vector_type(4))) float f32x4;

__device__ __forceinline__ float b2f(u16t u) {
    union { unsigned int i; float f; } v; v.i = ((unsigned int)u) << 16; return v.f;
}
__device__ __forceinline__ u16t f2b(float f) {
    __hip_bfloat16 h = __float2bfloat16(f);
    u16t u; memcpy(&u, &h, 2); return u;
}

// ---------------------------------------------------------------------------
// k_pre: block 0 = detect (stride flags); block 1 = prep (wl/wr/heg);
// blocks 2..129 = prepw (Wfrag MFMA layout). Merged to cut launch overhead.
// ---------------------------------------------------------------------------
__global__ void k_pre(const float* __restrict__ W, const float* __restrict__ We,
                      const float* __restrict__ emb, const float* __restrict__ al,
                      const float* __restrict__ ar, const float* __restrict__ ae,
                      const int* __restrict__ el, const int* __restrict__ ety,
                      float* __restrict__ wl, float* __restrict__ wr,
                      float* __restrict__ he, int* __restrict__ flag,
                      u16t* __restrict__ Wfrag) {
    int b = blockIdx.x;
    int tid = threadIdx.x;
    if (b == 0) {
        if (tid < 128) {
            int w = tid >> 6, lane = tid & 63;
            const int* p = (w == 0) ? el : ety;
            int x = p[2 * lane + 1];
            unsigned long long bal = __ballot(x != 0);
            if (lane == 0) flag[w] = (bal == 0ULL) ? 1 : 0;
        }
    } else if (b == 1) {
        __shared__ float wes[EF * NH];
        {
            int k = tid;
            for (int h = 0; h < NH; h++) {
                float accl = 0.f, accr = 0.f;
                for (int d = 0; d < 32; d++) {
                    float w = W[k * 128 + h * 32 + d];
                    accl += w * al[h * 32 + d];
                    accr += w * ar[h * 32 + d];
                }
                wl[k * NH + h] = accl;
                wr[k * NH + h] = accr;
            }
        }
        if (tid < EF) {
            int k = tid;
            for (int h = 0; h < NH; h++) {
                float s = 0.f;
                for (int d = 0; d < EF; d++)
                    s += We[k * (NH * EF) + h * EF + d] * ae[h * EF + d];
                wes[k * NH + h] = s;
            }
        }
        __syncthreads();
        if (tid < NET * NH) {
            int t = tid / NH, h = tid % NH;
            float s = 0.f;
            for (int k = 0; k < EF; k++)
                s += emb[t * EF + k] * wes[k * NH + h];
            he[tid] = s;
        }
    } else {
        int idx = (b - 2) * 256 + tid;  // 0..32767
        int j    = idx & 7;
        int lane = (idx >> 3) & 63;
        int ks   = (idx >> 9) & 7;
        int tile = idx >> 12;
        int n = tile * 16 + (lane & 15);
        int k = ks * 32 + (lane >> 4) * 8 + j;
        Wfrag[idx] = f2b(W[k * 128 + n]);
    }
}

// ---------------------------------------------------------------------------
// k_fuseA: [0,PBLK) bucket-partition of edges, DETERMINISTIC (zero global
// atomics): block b stages its bucket-sorted records to bucketbuf[b*EPB ...]
// (coalesced) and writes per-(block,bucket) counts/offsets hist2d/loff2d.
// [PBLK, PBLK+RDB) rowdot(head->hl). (tail rowdot removed: hr now computed
// in k_fuseB's GEMM epilogue from the MFMA accumulators — saves a full 50 MB
// re-read of tail.)
// Record = ti | (hi&63)<<16 | ty<<22 ; bucket = hi>>6.
// ---------------------------------------------------------------------------
__global__ void k_fuseA(const float* __restrict__ head,
                        const float* __restrict__ wl,
                        const int* __restrict__ el, const int* __restrict__ ety,
                        const int* __restrict__ flag,
                        int* __restrict__ hist2d, int* __restrict__ loff2d,
                        unsigned int* __restrict__ bucketbuf,
                        float* __restrict__ hl) {
    __shared__ unsigned int srec[EPB];
    __shared__ int hist[BKS];
    __shared__ int loff[BKS];
    __shared__ int psum[256];
    int b = blockIdx.x;
    int tid = threadIdx.x;
    if (b < PBLK) {
        int base = b * EPB;
        int wf = flag[0], wt = flag[1];
        for (int i = tid; i < BKS; i += 256) hist[i] = 0;
        __syncthreads();
        unsigned int rec[8];
        unsigned int br[8];
#pragma unroll
        for (int i = 0; i < 8; i++) {
            int e = base + i * 256 + tid;
            br[i] = 0xffffffffu;
            rec[i] = 0;
            if (e < NEDGE) {
                int hi = wf ? el[2 * (long long)e]           : el[e];
                int ti = wf ? el[2 * ((long long)NEDGE + e)] : el[NEDGE + e];
                int ty = wt ? ety[2 * (long long)e]          : ety[e];
                int bk = hi >> 6;
                int r = atomicAdd(&hist[bk], 1);
                rec[i] = (unsigned)ti | ((unsigned)(hi & 63) << 16) | ((unsigned)ty << 22);
                br[i]  = (unsigned)bk | ((unsigned)r << 16);
            }
        }
        __syncthreads();
        int s4[4]; int tsum = 0;
        if (tid < 196) {
#pragma unroll
            for (int j = 0; j < 4; j++) { s4[j] = hist[4 * tid + j]; tsum += s4[j]; }
        }
        psum[tid] = (tid < 196) ? tsum : 0;
        __syncthreads();
        for (int off = 1; off < 256; off <<= 1) {
            int v = (tid >= off) ? psum[tid - off] : 0;
            __syncthreads();
            psum[tid] += v;
            __syncthreads();
        }
        if (tid < 196) {
            int run = tid ? psum[tid - 1] : 0;
#pragma unroll
            for (int j = 0; j < 4; j++) {
                int bk = 4 * tid + j;
                loff[bk] = run;
                hist2d[b * BKS + bk] = s4[j];
                loff2d[b * BKS + bk] = run;
                run += s4[j];
            }
        }
        __syncthreads();
#pragma unroll
        for (int i = 0; i < 8; i++) {
            if (br[i] != 0xffffffffu) {
                int bk = br[i] & 0xffff;
                int r  = br[i] >> 16;
                srec[loff[bk] + r] = rec[i];
            }
        }
        __syncthreads();
        int tot = psum[255];
        for (int i = tid; i < tot; i += 256)
            bucketbuf[(size_t)b * EPB + i] = srec[i];
    } else {
        int bb = b - PBLK;               // head rowdot only
        int rowbase = bb * 32;
        int wave = tid >> 6;
        int g = (tid >> 4) & 3;
        int l = tid & 15;
        const float4* wv4 = (const float4*)wl;
        float4 acc[2];
#pragma unroll
        for (int rr = 0; rr < 2; rr++) {
            acc[rr].x = 0.f; acc[rr].y = 0.f; acc[rr].z = 0.f; acc[rr].w = 0.f;
            int row = rowbase + rr * 16 + wave * 4 + g;
            if (row < NNODE) {
                const float* xp = head + (size_t)row * INF + l * 4;
#pragma unroll
                for (int c = 0; c < 4; c++) {
                    float4 xv = *(const float4*)(xp + c * 64);
                    float xs[4] = {xv.x, xv.y, xv.z, xv.w};
#pragma unroll
                    for (int j = 0; j < 4; j++) {
                        float4 wvv = wv4[c * 64 + l * 4 + j];
                        acc[rr].x += xs[j] * wvv.x;
                        acc[rr].y += xs[j] * wvv.y;
                        acc[rr].z += xs[j] * wvv.z;
                        acc[rr].w += xs[j] * wvv.w;
                    }
                }
            }
        }
#pragma unroll
        for (int rr = 0; rr < 2; rr++) {
            // masks 8/4/2/1 never cross the 16-lane group boundary
#pragma unroll
            for (int off = 8; off > 0; off >>= 1) {
                acc[rr].x += __shfl_xor(acc[rr].x, off);
                acc[rr].y += __shfl_xor(acc[rr].y, off);
                acc[rr].z += __shfl_xor(acc[rr].z, off);
                acc[rr].w += __shfl_xor(acc[rr].w, off);
            }
            int row = rowbase + rr * 16 + wave * 4 + g;
            if (l == 0 && row < NNODE) ((float4*)hl)[row] = acc[rr];
        }
    }
}

// ---------------------------------------------------------------------------
// k_bsum: cursor[bk] = sum_b hist2d[b][bk]  (replaces global atomics)
// ---------------------------------------------------------------------------
__global__ void k_bsum(const int* __restrict__ hist2d, int* __restrict__ cursor) {
    __shared__ int red[256];
    int bk = blockIdx.x;          // 0..NBUCK-1
    int tid = threadIdx.x;
    int s = 0;
    for (int sb = tid; sb < PBLK; sb += 256) s += hist2d[sb * BKS + bk];
    red[tid] = s;
    __syncthreads();
    for (int off = 128; off > 0; off >>= 1) {
        if (tid < off) red[tid] += red[tid + off];
        __syncthreads();
    }
    if (tid == 0) cursor[bk] = red[0];
}

// ---------------------------------------------------------------------------
__global__ void k_bscan(const int* __restrict__ cursor, int* __restrict__ bstart,
                        int* __restrict__ row_start) {
    __shared__ int psum[256];
    int tid = threadIdx.x;
    int s4[4]; int tsum = 0;
    if (tid < 196) {
#pragma unroll
        for (int j = 0; j < 4; j++) {
            int bk = 4 * tid + j;
            s4[j] = (bk < NBUCK) ? cursor[bk] : 0;
            tsum += s4[j];
        }
    }
    psum[tid] = (tid < 196) ? tsum : 0;
    __syncthreads();
    for (int off = 1; off < 256; off <<= 1) {
        int v = (tid >= off) ? psum[tid - off] : 0;
        __syncthreads();
        psum[tid] += v;
        __syncthreads();
    }
    if (tid < 196) {
        int run = tid ? psum[tid - 1] : 0;
#pragma unroll
        for (int j = 0; j < 4; j++) {
            int bk = 4 * tid + j;
            if (bk < NBUCK) bstart[bk] = run;
            run += s4[j];
        }
    }
    if (tid == 255) {
        bstart[NBUCK] = psum[255];
        row_start[NNODE] = psum[255];
    }
}

// ---------------------------------------------------------------------------
// k_fuseB: [0,3125) MFMA gemm + hr-epilogue (hr[row][h] from f32 accumulators:
// wave w owns head w's 32 cols -> 8 FMA + 4-step shfl reduce); [3125,3907)
// per-bucket gather + LDS counting-sort -> cpack runs + row_start.
// cpack packing: ty<<18 | ti  (ty pre-shifted so k_agg's hes index is c>>16).
// ---------------------------------------------------------------------------
__global__ void k_fuseB(const float* __restrict__ X, const u16t* __restrict__ Wfrag,
                        const float* __restrict__ ar,
                        u16t* __restrict__ H, float* __restrict__ hr,
                        const unsigned int* __restrict__ bucketbuf,
                        const int* __restrict__ hist2d, const int* __restrict__ loff2d,
                        const int* __restrict__ bstart,
                        unsigned int* __restrict__ cpack, int* __restrict__ row_start) {
    __shared__ __attribute__((aligned(16))) u16t alds[16 * 264];
    __shared__ unsigned int lrec[BCAP];
    __shared__ unsigned int lord[BCAP];
    __shared__ int psum[256];
    __shared__ int cnt[64];
    __shared__ int sc[64];
    int b = blockIdx.x;
    int tid = threadIdx.x;
    if (b < 3125) {
        int rowbase = b * 16;
        for (int i = tid; i < 1024; i += 256) {
            int row = i >> 6;
            int kc = (i & 63) * 4;
            float4 v = *(const float4*)(X + (size_t)(rowbase + row) * INF + kc);
            u16t* d = alds + row * 264 + kc;
            d[0] = f2b(v.x); d[1] = f2b(v.y); d[2] = f2b(v.z); d[3] = f2b(v.w);
        }
        __syncthreads();
        int wave = tid >> 6, lane = tid & 63;
        int m = lane & 15, quad = lane >> 4;
        int t0 = wave * 2, t1 = t0 + 1;
        f32x4 acc0 = {0.f, 0.f, 0.f, 0.f};
        f32x4 acc1 = {0.f, 0.f, 0.f, 0.f};
#pragma unroll
        for (int ks = 0; ks < 8; ks++) {
            short8 a  = *(const short8*)(alds + m * 264 + ks * 32 + quad * 8);
            short8 b0 = *(const short8*)(Wfrag + (((t0 * 8 + ks) * 64 + lane) << 3));
            short8 b1 = *(const short8*)(Wfrag + (((t1 * 8 + ks) * 64 + lane) << 3));
            acc0 = __builtin_amdgcn_mfma_f32_16x16x32_bf16(a, b0, acc0, 0, 0, 0);
            acc1 = __builtin_amdgcn_mfma_f32_16x16x32_bf16(a, b1, acc1, 0, 0, 0);
        }
        u16t* Hp = H + (size_t)rowbase * 128;
#pragma unroll
        for (int r = 0; r < 4; r++) {
            int row = quad * 4 + r;
            Hp[(size_t)row * 128 + t0 * 16 + m] = f2b(acc0[r]);
            Hp[(size_t)row * 128 + t1 * 16 + m] = f2b(acc1[r]);
        }
        // hr epilogue: cols of wave w are head w's dims m (acc0) and m+16 (acc1)
        float arm0 = ar[wave * 32 + m];
        float arm1 = ar[wave * 32 + 16 + m];
#pragma unroll
        for (int r = 0; r < 4; r++) {
            float p = arm0 * acc0[r] + arm1 * acc1[r];
#pragma unroll
            for (int off = 8; off > 0; off >>= 1) p += __shfl_xor(p, off);
            if (m == 0) hr[(rowbase + quad * 4 + r) * 4 + wave] = p;
        }
    } else {
        int q = b - 3125;                 // bucket 0..781
        int bs = bstart[q];
        // gather this bucket's runs from the 782 block slices
        int c4[4], o4[4]; int tsum = 0;
        if (tid < 196) {
#pragma unroll
            for (int j = 0; j < 4; j++) {
                int sb = 4 * tid + j;
                c4[j] = 0; o4[j] = 0;
                if (sb < PBLK) {
                    c4[j] = hist2d[sb * BKS + q];
                    o4[j] = loff2d[sb * BKS + q];
                }
                tsum += c4[j];
            }
        }
        psum[tid] = (tid < 196) ? tsum : 0;
        __syncthreads();
        for (int off = 1; off < 256; off <<= 1) {
            int v = (tid >= off) ? psum[tid - off] : 0;
            __syncthreads();
            psum[tid] += v;
            __syncthreads();
        }
        if (tid < 196) {
            int run = tid ? psum[tid - 1] : 0;
#pragma unroll
            for (int j = 0; j < 4; j++) {
                int sb = 4 * tid + j;
                for (int k = 0; k < c4[j]; k++) {
                    int d = run + k;
                    if (d < BCAP)
                        lrec[d] = bucketbuf[(size_t)sb * EPB + o4[j] + k];
                }
                run += c4[j];
            }
        }
        if (tid < 64) cnt[tid] = 0;
        __syncthreads();
        int nrec = psum[255];
        if (nrec > BCAP) nrec = BCAP;
        unsigned int myr[10];
        int k2 = 0;
        for (int i = tid; i < nrec; i += 256) {
            int n = (lrec[i] >> 16) & 63;
            myr[k2++] = atomicAdd(&cnt[n], 1);
        }
        __syncthreads();
        if (tid < 64) sc[tid] = cnt[tid];
        __syncthreads();
        for (int off = 1; off < 64; off <<= 1) {
            int v = (tid >= off && tid < 64) ? sc[tid - off] : 0;
            __syncthreads();
            if (tid < 64) sc[tid] += v;
            __syncthreads();
        }
        k2 = 0;
        for (int i = tid; i < nrec; i += 256) {
            unsigned int rc = lrec[i];
            int n  = (rc >> 16) & 63;
            int ti = rc & 0xffff;
            int ty = rc >> 22;
            int pos = (sc[n] - cnt[n]) + (int)myr[k2++];
            lord[pos] = ((unsigned)ty << 18) | (unsigned)ti;
        }
        __syncthreads();
        for (int i = tid; i < nrec; i += 256)
            cpack[bs + i] = lord[i];
        if (tid < 64) {
            int node = q * 64 + tid;
            if (node < NNODE) row_start[node] = bs + (sc[tid] - cnt[tid]);
        }
    }
}

// ---------------------------------------------------------------------------
// k_agg: one wave per node, 16 lanes per head, 4 edges per iteration with
// full ILP. u32 address arithmetic, pre-shifted ty (hes idx = c>>16),
// branchless leaky via fmaxf(x, 0.2x).
// ---------------------------------------------------------------------------
__global__ void k_agg(const int* __restrict__ rs, const unsigned int* __restrict__ cpack,
                      const float* __restrict__ hl, const float* __restrict__ hr,
                      const float* __restrict__ heg, const u16t* __restrict__ ht,
                      float* __restrict__ den, float2* __restrict__ out) {
    __shared__ float hes[NET * NH];
    int tid = threadIdx.x;
    if (tid < NET * NH) hes[tid] = heg[tid];
    __syncthreads();
    int wave = tid >> 6, lane = tid & 63;
    int node = blockIdx.x * 4 + wave;
    int start = rs[node], end = rs[node + 1];
    unsigned h = (unsigned)(lane >> 4);
    unsigned lane2 = (unsigned)(lane << 1);
    float hlv = hl[(unsigned)node * 4u + h];
    const float* hesh = hes + h;           // hes idx = (c>>16) + h, c has ty<<18
    float a0 = 0.f, a1 = 0.f, s = 0.f;
    int j = start;
    for (; j + 4 <= end; j += 4) {
        unsigned c0 = cpack[j], c1 = cpack[j + 1], c2 = cpack[j + 2], c3 = cpack[j + 3];
        unsigned t0 = c0 & 0xffffu, t1 = c1 & 0xffffu;
        unsigned t2 = c2 & 0xffffu, t3 = c3 & 0xffffu;
        float r0 = hr[(t0 << 2) + h], r1 = hr[(t1 << 2) + h];
        float r2 = hr[(t2 << 2) + h], r3 = hr[(t3 << 2) + h];
        unsigned v0 = *(const unsigned*)(ht + ((t0 << 7) + lane2));
        unsigned v1 = *(const unsigned*)(ht + ((t1 << 7) + lane2));
        unsigned v2 = *(const unsigned*)(ht + ((t2 << 7) + lane2));
        unsigned v3 = *(const unsigned*)(ht + ((t3 << 7) + lane2));
        float x0 = hlv + r0 + hesh[c0 >> 16];
        float x1 = hlv + r1 + hesh[c1 >> 16];
        float x2 = hlv + r2 + hesh[c2 >> 16];
        float x3 = hlv + r3 + hesh[c3 >> 16];
        x0 = fmaxf(x0, 0.2f * x0);
        x1 = fmaxf(x1, 0.2f * x1);
        x2 = fmaxf(x2, 0.2f * x2);
        x3 = fmaxf(x3, 0.2f * x3);
        float e0 = __expf(x0), e1 = __expf(x1), e2 = __expf(x2), e3 = __expf(x3);
        union { unsigned u; float f; } w0, w1;
        w0.u = v0 << 16;          w1.u = v0 & 0xffff0000u;
        a0 += e0 * w0.f;          a1 += e0 * w1.f;
        w0.u = v1 << 16;          w1.u = v1 & 0xffff0000u;
        a0 += e1 * w0.f;          a1 += e1 * w1.f;
        w0.u = v2 << 16;          w1.u = v2 & 0xffff0000u;
        a0 += e2 * w0.f;          a1 += e2 * w1.f;
        w0.u = v3 << 16;          w1.u = v3 & 0xffff0000u;
        a0 += e3 * w0.f;          a1 += e3 * w1.f;
        s  += e0 + e1 + e2 + e3;
    }
    for (; j < end; j++) {
        unsigned c = cpack[j];
        unsigned ti = c & 0xffffu;
        float att = hlv + hr[(ti << 2) + h] + hesh[c >> 16];
        att = fmaxf(att, 0.2f * att);
        float exv = __expf(att);
        unsigned hv = *(const unsigned*)(ht + ((ti << 7) + lane2));
        union { unsigned u; float f; } w0, w1;
        w0.u = hv << 16;  w1.u = hv & 0xffff0000u;
        a0 += exv * w0.f;
        a1 += exv * w1.f;
        s  += exv;
    }
    if ((lane & 15) == 0) den[(unsigned)node * 4u + h] = s;
    float o0 = 0.f, o1 = 0.f;
    if (s > 0.f) { o0 = a0 / s; o1 = a1 / s; }
    o0 = o0 > 0.f ? o0 : expm1f(o0);
    o1 = o1 > 0.f ? o1 : expm1f(o1);
    float2 ov = {o0, o1};
    out[(size_t)node * 64 + lane] = ov;
}

// ---------------------------------------------------------------------------
__global__ void k_alpha(const int* __restrict__ el, const int* __restrict__ ety,
                        const int* __restrict__ flag,
                        const float* __restrict__ hl, const float* __restrict__ hr,
                        const float* __restrict__ heg, const float* __restrict__ den,
                        float* __restrict__ alpha) {
    __shared__ float hes[NET * NH];
    int tid = threadIdx.x;
    if (tid < NET * NH) hes[tid] = heg[tid];
    __syncthreads();
    int wf = flag[0], wt = flag[1];
    int e = blockIdx.x * 256 + tid;
    int hi = wf ? el[2 * (long long)e]           : el[e];
    int ti = wf ? el[2 * ((long long)NEDGE + e)] : el[NEDGE + e];
    int ty = wt ? ety[2 * (long long)e]          : ety[e];
    float4 l = ((const float4*)hl)[hi];
    float4 r = ((const float4*)hr)[ti];
    float4 d = ((const float4*)den)[hi];
    float v0 = l.x + r.x + hes[ty * 4 + 0];
    float v1 = l.y + r.y + hes[ty * 4 + 1];
    float v2 = l.z + r.z + hes[ty * 4 + 2];
    float v3 = l.w + r.w + hes[ty * 4 + 3];
    v0 = v0 > 0.f ? v0 : 0.2f * v0;
    v1 = v1 > 0.f ? v1 : 0.2f * v1;
    v2 = v2 > 0.f ? v2 : 0.2f * v2;
    v3 = v3 > 0.f ? v3 : 0.2f * v3;
    float4 o;
    o.x = d.x > 0.f ? __expf(v0) / d.x : 0.f;
    o.y = d.y > 0.f ? __expf(v1) / d.y : 0.f;
    o.z = d.z > 0.f ? __expf(v2) / d.z : 0.f;
    o.w = d.w > 0.f ? __expf(v3) / d.w : 0.f;
    ((float4*)alpha)[e] = o;
}

// ---------------------------------------------------------------------------
extern "C" void kernel_launch(void* const* d_in, const int* in_sizes, int n_in,
                              void* d_out, int out_size, void* d_ws, size_t ws_size,
                              hipStream_t stream) {
    const float* head = (const float*)d_in[0];
    const float* tail = (const float*)d_in[1];
    const float* W    = (const float*)d_in[2];
    const float* We   = (const float*)d_in[3];
    const float* emb  = (const float*)d_in[4];
    const float* al   = (const float*)d_in[5];
    const float* ar   = (const float*)d_in[6];
    const float* ae   = (const float*)d_in[7];
    const int*   el   = (const int*)d_in[8];
    const int*   ety  = (const int*)d_in[9];

    float* ws = (float*)d_ws;
    // ws layout (f32-slot offsets), ~2.7 MiB total
    float* hl       = ws;                       // 200,000
    float* hr       = ws + 200000;              // 200,000
    float* wl       = ws + 400000;              // 1,024
    float* wr       = ws + 401024;              // 1,024
    float* heg      = ws + 402048;              // 32
    int*   flag     = (int*)(ws + 402080);      // 16
    int*   bstart   = (int*)(ws + 402096);      // 784
    int*   cursor   = (int*)(ws + 402880);      // 784
    float* den      = ws + 403664;              // 200,000
    int*   row_start= (int*)(ws + 603664);      // 50,001 (+3 pad)
    u16t*  Wfrag    = (u16t*)(ws + 653668);     // 32,768 bf16 (16,384 f32)

    // d_out: f32 out [50000,128] then f32 alpha [E,4]
    float* outp   = (float*)d_out;              // 6,400,000 f32
    float* alphap = (float*)d_out + 6400000;    // 6,400,000 f32
    // scratch in alpha region until k_alpha overwrites: htail + cpack
    u16t*         htail = (u16t*)alphap;                       // 6.4M bf16
    unsigned int* cpack = (unsigned int*)(alphap + 3200000);   // 1.6M u32
    // scratch in out region (consumed by k_fuseB before k_agg writes out):
    // bucketbuf (block slices) + hist2d + loff2d
    unsigned int* bucketbuf = (unsigned int*)outp;             // 782*2048 u32 = 6.4 MB
    int* hist2d = (int*)outp + 1601536;                        // 782*784 ints
    int* loff2d = hist2d + 613088;                             // 782*784 ints

    k_pre<<<130, 256, 0, stream>>>(W, We, emb, al, ar, ae, el, ety,
                                   wl, wr, heg, flag, Wfrag);
    k_fuseA<<<PBLK + RDB, 256, 0, stream>>>(head, wl, el, ety, flag,
                                            hist2d, loff2d, bucketbuf, hl);
    k_bsum<<<NBUCK, 256, 0, stream>>>(hist2d, cursor);
    k_bscan<<<1, 256, 0, stream>>>(cursor, bstart, row_start);
    k_fuseB<<<3125 + NBUCK, 256, 0, stream>>>(tail, Wfrag, ar, htail, hr, bucketbuf,
                                              hist2d, loff2d, bstart, cpack, row_start);
    k_agg<<<NNODE / 4, 256, 0, stream>>>(row_start, cpack, hl, hr, heg, htail,
                                         den, (float2*)outp);
    k_alpha<<<NEDGE / 256, 256, 0, stream>>>(el, ety, flag, hl, hr, heg, den, alphap);
}

// Round 7
// 317.194 us; speedup vs baseline: 1.1868x; 1.0277x over previous
//
#include <hip/hip_runtime.h>
#include <hip/hip_bf16.h>
#include <string.h>

#define NNODE 50000
#define NEDGE 1600000
#define INF   256
#define NH    4
#define EF    64
#define NET   5

#define NBUCK 782     // bucket = hi>>6 (64 nodes each); 50000/64 -> 0..781
#define BCAP  2560    // per-bucket capacity; mean 2048, sd ~45 -> 11 sigma
#define EPB   2048    // edges per partition block
#define PBLK  782     // partition blocks (782*2048 >= E)
#define BKS   784     // padded bucket-row stride
#define RDB   1563    // head-rowdot blocks, 32 rows each (1563*32 >= 50000)

typedef unsigned short u16t;
typedef __attribute__((ext_vector_type(8))) short short8;
typedef __attribute__((ext_vector_type(4))) float f32x4;

__device__ __forceinline__ float b2f(u16t u) {
    union { unsigned int i; float f; } v; v.i = ((unsigned int)u) << 16; return v.f;
}
__device__ __forceinline__ u16t f2b(float f) {
    __hip_bfloat16 h = __float2bfloat16(f);
    u16t u; memcpy(&u, &h, 2); return u;
}

// ---------------------------------------------------------------------------
// k_pre: block 0 = detect (stride flags); block 1 = prep (wl/wr/heg);
// blocks 2..129 = prepw (Wfrag MFMA layout). Merged to cut launch overhead.
// ---------------------------------------------------------------------------
__global__ void k_pre(const float* __restrict__ W, const float* __restrict__ We,
                      const float* __restrict__ emb, const float* __restrict__ al,
                      const float* __restrict__ ar, const float* __restrict__ ae,
                      const int* __restrict__ el, const int* __restrict__ ety,
                      float* __restrict__ wl, float* __restrict__ wr,
                      float* __restrict__ he, int* __restrict__ flag,
                      u16t* __restrict__ Wfrag) {
    int b = blockIdx.x;
    int tid = threadIdx.x;
    if (b == 0) {
        if (tid < 128) {
            int w = tid >> 6, lane = tid & 63;
            const int* p = (w == 0) ? el : ety;
            int x = p[2 * lane + 1];
            unsigned long long bal = __ballot(x != 0);
            if (lane == 0) flag[w] = (bal == 0ULL) ? 1 : 0;
        }
    } else if (b == 1) {
        __shared__ float wes[EF * NH];
        {
            int k = tid;
            for (int h = 0; h < NH; h++) {
                float accl = 0.f, accr = 0.f;
                for (int d = 0; d < 32; d++) {
                    float w = W[k * 128 + h * 32 + d];
                    accl += w * al[h * 32 + d];
                    accr += w * ar[h * 32 + d];
                }
                wl[k * NH + h] = accl;
                wr[k * NH + h] = accr;
            }
        }
        if (tid < EF) {
            int k = tid;
            for (int h = 0; h < NH; h++) {
                float s = 0.f;
                for (int d = 0; d < EF; d++)
                    s += We[k * (NH * EF) + h * EF + d] * ae[h * EF + d];
                wes[k * NH + h] = s;
            }
        }
        __syncthreads();
        if (tid < NET * NH) {
            int t = tid / NH, h = tid % NH;
            float s = 0.f;
            for (int k = 0; k < EF; k++)
                s += emb[t * EF + k] * wes[k * NH + h];
            he[tid] = s;
        }
    } else {
        int idx = (b - 2) * 256 + tid;  // 0..32767
        int j    = idx & 7;
        int lane = (idx >> 3) & 63;
        int ks   = (idx >> 9) & 7;
        int tile = idx >> 12;
        int n = tile * 16 + (lane & 15);
        int k = ks * 32 + (lane >> 4) * 8 + j;
        Wfrag[idx] = f2b(W[k * 128 + n]);
    }
}

// ---------------------------------------------------------------------------
// k_fuseA: [0,PBLK) bucket-partition of edges, DETERMINISTIC (zero global
// atomics): block b stages its bucket-sorted records to bucketbuf[b*EPB ...]
// (coalesced) and writes per-(block,bucket) counts/offsets hist2d/loff2d.
// [PBLK, PBLK+RDB) rowdot(head->hl). Record = ti | (hi&63)<<16 | ty<<22.
// ---------------------------------------------------------------------------
__global__ void k_fuseA(const float* __restrict__ head,
                        const float* __restrict__ wl,
                        const int* __restrict__ el, const int* __restrict__ ety,
                        const int* __restrict__ flag,
                        int* __restrict__ hist2d, int* __restrict__ loff2d,
                        unsigned int* __restrict__ bucketbuf,
                        float* __restrict__ hl) {
    __shared__ unsigned int srec[EPB];
    __shared__ int hist[BKS];
    __shared__ int loff[BKS];
    __shared__ int psum[256];
    int b = blockIdx.x;
    int tid = threadIdx.x;
    if (b < PBLK) {
        int base = b * EPB;
        int wf = flag[0], wt = flag[1];
        for (int i = tid; i < BKS; i += 256) hist[i] = 0;
        __syncthreads();
        unsigned int rec[8];
        unsigned int br[8];
#pragma unroll
        for (int i = 0; i < 8; i++) {
            int e = base + i * 256 + tid;
            br[i] = 0xffffffffu;
            rec[i] = 0;
            if (e < NEDGE) {
                int hi = wf ? el[2 * (long long)e]           : el[e];
                int ti = wf ? el[2 * ((long long)NEDGE + e)] : el[NEDGE + e];
                int ty = wt ? ety[2 * (long long)e]          : ety[e];
                int bk = hi >> 6;
                int r = atomicAdd(&hist[bk], 1);
                rec[i] = (unsigned)ti | ((unsigned)(hi & 63) << 16) | ((unsigned)ty << 22);
                br[i]  = (unsigned)bk | ((unsigned)r << 16);
            }
        }
        __syncthreads();
        int s4[4]; int tsum = 0;
        if (tid < 196) {
#pragma unroll
            for (int j = 0; j < 4; j++) { s4[j] = hist[4 * tid + j]; tsum += s4[j]; }
        }
        psum[tid] = (tid < 196) ? tsum : 0;
        __syncthreads();
        for (int off = 1; off < 256; off <<= 1) {
            int v = (tid >= off) ? psum[tid - off] : 0;
            __syncthreads();
            psum[tid] += v;
            __syncthreads();
        }
        if (tid < 196) {
            int run = tid ? psum[tid - 1] : 0;
#pragma unroll
            for (int j = 0; j < 4; j++) {
                int bk = 4 * tid + j;
                loff[bk] = run;
                hist2d[b * BKS + bk] = s4[j];
                loff2d[b * BKS + bk] = run;
                run += s4[j];
            }
        }
        __syncthreads();
#pragma unroll
        for (int i = 0; i < 8; i++) {
            if (br[i] != 0xffffffffu) {
                int bk = br[i] & 0xffff;
                int r  = br[i] >> 16;
                srec[loff[bk] + r] = rec[i];
            }
        }
        __syncthreads();
        int tot = psum[255];
        for (int i = tid; i < tot; i += 256)
            bucketbuf[(size_t)b * EPB + i] = srec[i];
    } else {
        int bb = b - PBLK;               // head rowdot only
        int rowbase = bb * 32;
        int wave = tid >> 6;
        int g = (tid >> 4) & 3;
        int l = tid & 15;
        const float4* wv4 = (const float4*)wl;
        float4 acc[2];
#pragma unroll
        for (int rr = 0; rr < 2; rr++) {
            acc[rr].x = 0.f; acc[rr].y = 0.f; acc[rr].z = 0.f; acc[rr].w = 0.f;
            int row = rowbase + rr * 16 + wave * 4 + g;
            if (row < NNODE) {
                const float* xp = head + (size_t)row * INF + l * 4;
#pragma unroll
                for (int c = 0; c < 4; c++) {
                    float4 xv = *(const float4*)(xp + c * 64);
                    float xs[4] = {xv.x, xv.y, xv.z, xv.w};
#pragma unroll
                    for (int j = 0; j < 4; j++) {
                        float4 wvv = wv4[c * 64 + l * 4 + j];
                        acc[rr].x += xs[j] * wvv.x;
                        acc[rr].y += xs[j] * wvv.y;
                        acc[rr].z += xs[j] * wvv.z;
                        acc[rr].w += xs[j] * wvv.w;
                    }
                }
            }
        }
#pragma unroll
        for (int rr = 0; rr < 2; rr++) {
            // masks 8/4/2/1 never cross the 16-lane group boundary
#pragma unroll
            for (int off = 8; off > 0; off >>= 1) {
                acc[rr].x += __shfl_xor(acc[rr].x, off);
                acc[rr].y += __shfl_xor(acc[rr].y, off);
                acc[rr].z += __shfl_xor(acc[rr].z, off);
                acc[rr].w += __shfl_xor(acc[rr].w, off);
            }
            int row = rowbase + rr * 16 + wave * 4 + g;
            if (l == 0 && row < NNODE) ((float4*)hl)[row] = acc[rr];
        }
    }
}

// ---------------------------------------------------------------------------
// k_fuseB: [0,3125) MFMA gemm + hr-epilogue; [3125,3907) per-bucket gather
// (from block slices via hist2d/loff2d) + LDS counting-sort -> cpack at the
// FIXED region q*BCAP (no global prefix sums -> k_bsum/k_bscan eliminated),
// plus per-node row_start/row_end.
// cpack packing: ty<<18 | ti  (ty pre-shifted so k_agg's hes index is c>>16).
// ---------------------------------------------------------------------------
__global__ void k_fuseB(const float* __restrict__ X, const u16t* __restrict__ Wfrag,
                        const float* __restrict__ ar,
                        u16t* __restrict__ H, float* __restrict__ hr,
                        const unsigned int* __restrict__ bucketbuf,
                        const int* __restrict__ hist2d, const int* __restrict__ loff2d,
                        unsigned int* __restrict__ cpack,
                        int* __restrict__ row_start, int* __restrict__ row_end) {
    __shared__ __attribute__((aligned(16))) u16t alds[16 * 264];
    __shared__ unsigned int lrec[BCAP];
    __shared__ unsigned int lord[BCAP];
    __shared__ int psum[256];
    __shared__ int cnt[64];
    __shared__ int sc[64];
    int b = blockIdx.x;
    int tid = threadIdx.x;
    if (b < 3125) {
        int rowbase = b * 16;
        for (int i = tid; i < 1024; i += 256) {
            int row = i >> 6;
            int kc = (i & 63) * 4;
            float4 v = *(const float4*)(X + (size_t)(rowbase + row) * INF + kc);
            u16t* d = alds + row * 264 + kc;
            d[0] = f2b(v.x); d[1] = f2b(v.y); d[2] = f2b(v.z); d[3] = f2b(v.w);
        }
        __syncthreads();
        int wave = tid >> 6, lane = tid & 63;
        int m = lane & 15, quad = lane >> 4;
        int t0 = wave * 2, t1 = t0 + 1;
        f32x4 acc0 = {0.f, 0.f, 0.f, 0.f};
        f32x4 acc1 = {0.f, 0.f, 0.f, 0.f};
#pragma unroll
        for (int ks = 0; ks < 8; ks++) {
            short8 a  = *(const short8*)(alds + m * 264 + ks * 32 + quad * 8);
            short8 b0 = *(const short8*)(Wfrag + (((t0 * 8 + ks) * 64 + lane) << 3));
            short8 b1 = *(const short8*)(Wfrag + (((t1 * 8 + ks) * 64 + lane) << 3));
            acc0 = __builtin_amdgcn_mfma_f32_16x16x32_bf16(a, b0, acc0, 0, 0, 0);
            acc1 = __builtin_amdgcn_mfma_f32_16x16x32_bf16(a, b1, acc1, 0, 0, 0);
        }
        u16t* Hp = H + (size_t)rowbase * 128;
#pragma unroll
        for (int r = 0; r < 4; r++) {
            int row = quad * 4 + r;
            Hp[(size_t)row * 128 + t0 * 16 + m] = f2b(acc0[r]);
            Hp[(size_t)row * 128 + t1 * 16 + m] = f2b(acc1[r]);
        }
        // hr epilogue: cols of wave w are head w's dims m (acc0) and m+16 (acc1)
        float arm0 = ar[wave * 32 + m];
        float arm1 = ar[wave * 32 + 16 + m];
#pragma unroll
        for (int r = 0; r < 4; r++) {
            float p = arm0 * acc0[r] + arm1 * acc1[r];
#pragma unroll
            for (int off = 8; off > 0; off >>= 1) p += __shfl_xor(p, off);
            if (m == 0) hr[(rowbase + quad * 4 + r) * 4 + wave] = p;
        }
    } else {
        int q = b - 3125;                 // bucket 0..781
        int bs = q * BCAP;                // fixed region, no prefix sums
        // gather this bucket's runs from the 782 block slices
        int c4[4], o4[4]; int tsum = 0;
        if (tid < 196) {
#pragma unroll
            for (int j = 0; j < 4; j++) {
                int sb = 4 * tid + j;
                c4[j] = 0; o4[j] = 0;
                if (sb < PBLK) {
                    c4[j] = hist2d[sb * BKS + q];
                    o4[j] = loff2d[sb * BKS + q];
                }
                tsum += c4[j];
            }
        }
        psum[tid] = (tid < 196) ? tsum : 0;
        __syncthreads();
        for (int off = 1; off < 256; off <<= 1) {
            int v = (tid >= off) ? psum[tid - off] : 0;
            __syncthreads();
            psum[tid] += v;
            __syncthreads();
        }
        if (tid < 196) {
            int run = tid ? psum[tid - 1] : 0;
#pragma unroll
            for (int j = 0; j < 4; j++) {
                int sb = 4 * tid + j;
                for (int k = 0; k < c4[j]; k++) {
                    int d = run + k;
                    if (d < BCAP)
                        lrec[d] = bucketbuf[(size_t)sb * EPB + o4[j] + k];
                }
                run += c4[j];
            }
        }
        if (tid < 64) cnt[tid] = 0;
        __syncthreads();
        int nrec = psum[255];
        if (nrec > BCAP) nrec = BCAP;
        unsigned int myr[10];
        int k2 = 0;
        for (int i = tid; i < nrec; i += 256) {
            int n = (lrec[i] >> 16) & 63;
            myr[k2++] = atomicAdd(&cnt[n], 1);
        }
        __syncthreads();
        if (tid < 64) sc[tid] = cnt[tid];
        __syncthreads();
        for (int off = 1; off < 64; off <<= 1) {
            int v = (tid >= off && tid < 64) ? sc[tid - off] : 0;
            __syncthreads();
            if (tid < 64) sc[tid] += v;
            __syncthreads();
        }
        k2 = 0;
        for (int i = tid; i < nrec; i += 256) {
            unsigned int rc = lrec[i];
            int n  = (rc >> 16) & 63;
            int ti = rc & 0xffff;
            int ty = rc >> 22;
            int pos = (sc[n] - cnt[n]) + (int)myr[k2++];
            lord[pos] = ((unsigned)ty << 18) | (unsigned)ti;
        }
        __syncthreads();
        for (int i = tid; i < nrec; i += 256)
            cpack[bs + i] = lord[i];
        if (tid < 64) {
            int node = q * 64 + tid;
            if (node < NNODE) {
                row_start[node] = bs + (sc[tid] - cnt[tid]);
                row_end[node]   = bs + sc[tid];
            }
        }
    }
}

// ---------------------------------------------------------------------------
// k_agg: one wave per node, 16 lanes per head, 4 edges per iteration with
// full ILP. u32 address arithmetic, pre-shifted ty (hes idx = c>>16),
// branchless leaky via fmaxf(x, 0.2x). Range = [rs[node], re[node]).
// ---------------------------------------------------------------------------
__global__ void k_agg(const int* __restrict__ rs, const int* __restrict__ re,
                      const unsigned int* __restrict__ cpack,
                      const float* __restrict__ hl, const float* __restrict__ hr,
                      const float* __restrict__ heg, const u16t* __restrict__ ht,
                      float* __restrict__ den, float2* __restrict__ out) {
    __shared__ float hes[NET * NH];
    int tid = threadIdx.x;
    if (tid < NET * NH) hes[tid] = heg[tid];
    __syncthreads();
    int wave = tid >> 6, lane = tid & 63;
    int node = blockIdx.x * 4 + wave;
    int start = rs[node], end = re[node];
    unsigned h = (unsigned)(lane >> 4);
    unsigned lane2 = (unsigned)(lane << 1);
    float hlv = hl[(unsigned)node * 4u + h];
    const float* hesh = hes + h;           // hes idx = (c>>16) + h, c has ty<<18
    float a0 = 0.f, a1 = 0.f, s = 0.f;
    int j = start;
    for (; j + 4 <= end; j += 4) {
        unsigned c0 = cpack[j], c1 = cpack[j + 1], c2 = cpack[j + 2], c3 = cpack[j + 3];
        unsigned t0 = c0 & 0xffffu, t1 = c1 & 0xffffu;
        unsigned t2 = c2 & 0xffffu, t3 = c3 & 0xffffu;
        float r0 = hr[(t0 << 2) + h], r1 = hr[(t1 << 2) + h];
        float r2 = hr[(t2 << 2) + h], r3 = hr[(t3 << 2) + h];
        unsigned v0 = *(const unsigned*)(ht + ((t0 << 7) + lane2));
        unsigned v1 = *(const unsigned*)(ht + ((t1 << 7) + lane2));
        unsigned v2 = *(const unsigned*)(ht + ((t2 << 7) + lane2));
        unsigned v3 = *(const unsigned*)(ht + ((t3 << 7) + lane2));
        float x0 = hlv + r0 + hesh[c0 >> 16];
        float x1 = hlv + r1 + hesh[c1 >> 16];
        float x2 = hlv + r2 + hesh[c2 >> 16];
        float x3 = hlv + r3 + hesh[c3 >> 16];
        x0 = fmaxf(x0, 0.2f * x0);
        x1 = fmaxf(x1, 0.2f * x1);
        x2 = fmaxf(x2, 0.2f * x2);
        x3 = fmaxf(x3, 0.2f * x3);
        float e0 = __expf(x0), e1 = __expf(x1), e2 = __expf(x2), e3 = __expf(x3);
        union { unsigned u; float f; } w0, w1;
        w0.u = v0 << 16;          w1.u = v0 & 0xffff0000u;
        a0 += e0 * w0.f;          a1 += e0 * w1.f;
        w0.u = v1 << 16;          w1.u = v1 & 0xffff0000u;
        a0 += e1 * w0.f;          a1 += e1 * w1.f;
        w0.u = v2 << 16;          w1.u = v2 & 0xffff0000u;
        a0 += e2 * w0.f;          a1 += e2 * w1.f;
        w0.u = v3 << 16;          w1.u = v3 & 0xffff0000u;
        a0 += e3 * w0.f;          a1 += e3 * w1.f;
        s  += e0 + e1 + e2 + e3;
    }
    for (; j < end; j++) {
        unsigned c = cpack[j];
        unsigned ti = c & 0xffffu;
        float att = hlv + hr[(ti << 2) + h] + hesh[c >> 16];
        att = fmaxf(att, 0.2f * att);
        float exv = __expf(att);
        unsigned hv = *(const unsigned*)(ht + ((ti << 7) + lane2));
        union { unsigned u; float f; } w0, w1;
        w0.u = hv << 16;  w1.u = hv & 0xffff0000u;
        a0 += exv * w0.f;
        a1 += exv * w1.f;
        s  += exv;
    }
    if ((lane & 15) == 0) den[(unsigned)node * 4u + h] = s;
    float o0 = 0.f, o1 = 0.f;
    if (s > 0.f) { o0 = a0 / s; o1 = a1 / s; }
    o0 = o0 > 0.f ? o0 : expm1f(o0);
    o1 = o1 > 0.f ? o1 : expm1f(o1);
    float2 ov = {o0, o1};
    out[(size_t)node * 64 + lane] = ov;
}

// ---------------------------------------------------------------------------
__global__ void k_alpha(const int* __restrict__ el, const int* __restrict__ ety,
                        const int* __restrict__ flag,
                        const float* __restrict__ hl, const float* __restrict__ hr,
                        const float* __restrict__ heg, const float* __restrict__ den,
                        float* __restrict__ alpha) {
    __shared__ float hes[NET * NH];
    int tid = threadIdx.x;
    if (tid < NET * NH) hes[tid] = heg[tid];
    __syncthreads();
    int wf = flag[0], wt = flag[1];
    int e = blockIdx.x * 256 + tid;
    int hi = wf ? el[2 * (long long)e]           : el[e];
    int ti = wf ? el[2 * ((long long)NEDGE + e)] : el[NEDGE + e];
    int ty = wt ? ety[2 * (long long)e]          : ety[e];
    float4 l = ((const float4*)hl)[hi];
    float4 r = ((const float4*)hr)[ti];
    float4 d = ((const float4*)den)[hi];
    float v0 = l.x + r.x + hes[ty * 4 + 0];
    float v1 = l.y + r.y + hes[ty * 4 + 1];
    float v2 = l.z + r.z + hes[ty * 4 + 2];
    float v3 = l.w + r.w + hes[ty * 4 + 3];
    v0 = v0 > 0.f ? v0 : 0.2f * v0;
    v1 = v1 > 0.f ? v1 : 0.2f * v1;
    v2 = v2 > 0.f ? v2 : 0.2f * v2;
    v3 = v3 > 0.f ? v3 : 0.2f * v3;
    float4 o;
    o.x = d.x > 0.f ? __expf(v0) / d.x : 0.f;
    o.y = d.y > 0.f ? __expf(v1) / d.y : 0.f;
    o.z = d.z > 0.f ? __expf(v2) / d.z : 0.f;
    o.w = d.w > 0.f ? __expf(v3) / d.w : 0.f;
    ((float4*)alpha)[e] = o;
}

// ---------------------------------------------------------------------------
extern "C" void kernel_launch(void* const* d_in, const int* in_sizes, int n_in,
                              void* d_out, int out_size, void* d_ws, size_t ws_size,
                              hipStream_t stream) {
    const float* head = (const float*)d_in[0];
    const float* tail = (const float*)d_in[1];
    const float* W    = (const float*)d_in[2];
    const float* We   = (const float*)d_in[3];
    const float* emb  = (const float*)d_in[4];
    const float* al   = (const float*)d_in[5];
    const float* ar   = (const float*)d_in[6];
    const float* ae   = (const float*)d_in[7];
    const int*   el   = (const int*)d_in[8];
    const int*   ety  = (const int*)d_in[9];

    float* ws = (float*)d_ws;
    // ws layout (f32-slot offsets), ~2.7 MiB total
    float* hl       = ws;                       // 200,000
    float* hr       = ws + 200000;              // 200,000
    float* wl       = ws + 400000;              // 1,024
    float* wr       = ws + 401024;              // 1,024
    float* heg      = ws + 402048;              // 32
    int*   flag     = (int*)(ws + 402080);      // 16
    float* den      = ws + 403664;              // 200,000
    int*   row_start= (int*)(ws + 603664);      // 50,000 (+4 pad)
    u16t*  Wfrag    = (u16t*)(ws + 653668);     // 32,768 bf16 (16,384 f32)

    // d_out: f32 out [50000,128] then f32 alpha [E,4]
    float* outp   = (float*)d_out;              // 6,400,000 f32
    float* alphap = (float*)d_out + 6400000;    // 6,400,000 f32
    // scratch in alpha region until k_alpha overwrites:
    //   htail (12.8 MB) + cpack (fixed NBUCK*BCAP = 8.0 MB) + row_end (200 KB)
    u16t*         htail = (u16t*)alphap;                       // 6.4M bf16
    unsigned int* cpack = (unsigned int*)(alphap + 3200000);   // 782*2560 u32
    int*          row_end = (int*)(alphap + 5220000);          // 50,000 int
    // scratch in out region (consumed by k_fuseB before k_agg writes out):
    // bucketbuf (block slices) + hist2d + loff2d
    unsigned int* bucketbuf = (unsigned int*)outp;             // 782*2048 u32 = 6.4 MB
    int* hist2d = (int*)outp + 1601536;                        // 782*784 ints
    int* loff2d = hist2d + 613088;                             // 782*784 ints

    k_pre<<<130, 256, 0, stream>>>(W, We, emb, al, ar, ae, el, ety,
                                   wl, wr, heg, flag, Wfrag);
    k_fuseA<<<PBLK + RDB, 256, 0, stream>>>(head, wl, el, ety, flag,
                                            hist2d, loff2d, bucketbuf, hl);
    k_fuseB<<<3125 + NBUCK, 256, 0, stream>>>(tail, Wfrag, ar, htail, hr, bucketbuf,
                                              hist2d, loff2d, cpack,
                                              row_start, row_end);
    k_agg<<<NNODE / 4, 256, 0, stream>>>(row_start, row_end, cpack, hl, hr, heg,
                                         htail, den, (float2*)outp);
    k_alpha<<<NEDGE / 256, 256, 0, stream>>>(el, ety, flag, hl, hr, heg, den, alphap);
}